// Round 2
// baseline (538.792 us; speedup 1.0000x reference)
//
#include <hip/hip_runtime.h>
#include <hip/hip_bf16.h>

// Problem constants
// B=16, SEQ=512, NF=32, E=128, HID=512, PRED=96, N_FFT=64, HOP=32, TOPM=32
// W=17, F=33, LAM=0.01
#define LAM 0.01f

typedef __attribute__((ext_vector_type(8))) short v8s;
typedef __attribute__((ext_vector_type(4))) float v4f;

static __device__ __forceinline__ unsigned short f2bf(float f) {
    union { float f; unsigned int u; } v; v.f = f;
    unsigned int u = v.u;
    u += 0x7fffu + ((u >> 16) & 1u);   // round-to-nearest-even
    return (unsigned short)(u >> 16);
}
static __device__ __forceinline__ float bf2f(unsigned short h) {
    union { unsigned int u; float f; } c; c.u = ((unsigned int)h) << 16;
    return c.f;
}

// Workspace layout (bytes)
#define OFF_COEF 0ull                                  // 17*128*8 f32   = 69,632
#define OFF_V    69632ull                              // 8704*32 float2 = 2,228,224
#define OFF_BINS 2297856ull                            // 8704*32 int    = 1,114,112
#define OFF_XO   3411968ull                            // xo: f32 134MB or bf16 67MB
// OFF_HP computed at launch (after xo)

// ---------------------------------------------------------------------------
// Kernel A: coef[w][e][j] : j=0..5 -> emb . Wj[w,:,e]; j=6 -> br-LAM; j=7 -> bi-LAM
// ---------------------------------------------------------------------------
__global__ __launch_bounds__(128) void coef_kernel(
    const float* __restrict__ emb,
    const float* __restrict__ Wr, const float* __restrict__ Wi,
    const float* __restrict__ Wrl, const float* __restrict__ Wil,
    const float* __restrict__ Wrr, const float* __restrict__ Wir,
    const float* __restrict__ br, const float* __restrict__ bi,
    float* __restrict__ coef)
{
    int w = blockIdx.x, j = blockIdx.y, e = threadIdx.x;
    float out;
    if (j < 6) {
        const float* Wj;
        switch (j) {
            case 0: Wj = Wr; break; case 1: Wj = Wi; break;
            case 2: Wj = Wrl; break; case 3: Wj = Wil; break;
            case 4: Wj = Wrr; break; default: Wj = Wir; break;
        }
        const float* p = Wj + (size_t)w * 16384 + e;
        float acc = 0.f;
        #pragma unroll 8
        for (int ep = 0; ep < 128; ++ep) acc = fmaf(emb[ep], p[ep * 128], acc);
        out = acc;
    } else if (j == 6) {
        out = br[w * 128 + e] - LAM;
    } else {
        out = bi[w * 128 + e] - LAM;
    }
    coef[((size_t)(w * 128 + e)) * 8 + j] = out;
}

// ---------------------------------------------------------------------------
// Kernel B: per (b,n): windowed 64-pt DFT, 17 frames x 33 bins, rank |S|,
// store top-32 values V (rank-ordered) + bin indices.
// ---------------------------------------------------------------------------
__global__ __launch_bounds__(256) void stft_kernel(
    const float* __restrict__ x, float2* __restrict__ V, int* __restrict__ bins)
{
    __shared__ float sig[576];
    __shared__ float winT[64];
    __shared__ float2 tw[64];
    __shared__ float2 Sbuf[17 * 33];
    __shared__ float absb[17 * 33];

    const int blk = blockIdx.x;
    const int b = blk >> 5, n = blk & 31;
    const int tid = threadIdx.x;
    const float C64 = 0.09817477042468103f; // 2*pi/64

    if (tid < 64) {
        float ang = (float)tid * C64;
        winT[tid] = 0.5f - 0.5f * cosf(ang);
        tw[tid] = make_float2(cosf(ang), sinf(ang));   // accurate libm: top-k tie safety
    }
    for (int l = tid; l < 576; l += 256) {
        int t = (l < 32) ? (32 - l) : ((l < 544) ? (l - 32) : (1054 - l)); // reflect pad
        sig[l] = x[(size_t)b * 16384 + t * 32 + n];
    }
    __syncthreads();

    for (int task = tid; task < 561; task += 256) {
        int w = task / 33, f = task - w * 33;
        float sr = 0.f, si = 0.f;
        int base = w * 32;
        for (int t = 0; t < 64; ++t) {
            float sw = sig[base + t] * winT[t];
            float2 cs = tw[(f * t) & 63];
            sr = fmaf(sw, cs.x, sr);
            si = fmaf(sw, -cs.y, si);
        }
        Sbuf[task] = make_float2(sr, si);
        absb[task] = sqrtf(fmaf(sr, sr, si * si));
    }
    __syncthreads();

    for (int task = tid; task < 561; task += 256) {
        int w = task / 33, f = task - w * 33;
        float a = absb[task];
        int base = w * 33, rank = 0;
        for (int j = 0; j < 33; ++j) {
            float aj = absb[base + j];
            rank += (aj > a) || (aj == a && j < f);   // stable: lower index first
        }
        if (rank < 32) {
            size_t o = ((size_t)blk * 17 + w) * 32 + rank;
            V[o] = Sbuf[task];
            bins[o] = f;
        }
    }
}

// ---------------------------------------------------------------------------
// Kernel C: mid — y = max(lin+bias-LAM,0) bf16; irfft basis from bins; MFMA
// 64x128 time tile; hann; rolling-register OLA; /env; + x*emb; write xo.
// grid 512, block 256 (4 waves). XO32: write f32 plane else bf16.
// ---------------------------------------------------------------------------
#define MID_ROLL(J0, J1, J2, J3)                                                \
    {                                                                           \
        _Pragma("unroll") for (int e2 = 0; e2 < 2; ++e2)                        \
        _Pragma("unroll") for (int i = 0; i < 4; ++i) {                         \
            roll[e2][J0][i] = fmaf(acc[0][e2][i], win16[0][i], roll[e2][J0][i]);\
            roll[e2][J1][i] = fmaf(acc[1][e2][i], win16[1][i], roll[e2][J1][i]);\
            roll[e2][J2][i] = fmaf(acc[2][e2][i], win16[2][i], roll[e2][J2][i]);\
            roll[e2][J3][i] = fmaf(acc[3][e2][i], win16[3][i], roll[e2][J3][i]);\
        }                                                                       \
    }

#define MID_FLUSH(JJA, JJB)                                                     \
    {                                                                           \
        _Pragma("unroll") for (int i = 0; i < 4; ++i) {                         \
            int tp = 32 * (w - 1) + q * 4 + i;                                  \
            float xb = x[xrow + tp * 32];                                       \
            _Pragma("unroll") for (int e2 = 0; e2 < 2; ++e2) {                  \
                float val = fmaf(roll[e2][JJA][i], renv[0][i], xb * emb2[e2]);  \
                size_t off = xobase + (size_t)tp * 128 + ebase[e2];             \
                if (XO32) xo32[off] = val; else xo16[off] = f2bf(val);          \
                roll[e2][JJA][i] = 0.f;                                         \
            }                                                                   \
            int tp2 = tp + 16;                                                  \
            float xb2 = x[xrow + tp2 * 32];                                     \
            _Pragma("unroll") for (int e2 = 0; e2 < 2; ++e2) {                  \
                float val = fmaf(roll[e2][JJB][i], renv[1][i], xb2 * emb2[e2]); \
                size_t off = xobase + (size_t)tp2 * 128 + ebase[e2];            \
                if (XO32) xo32[off] = val; else xo16[off] = f2bf(val);          \
                roll[e2][JJB][i] = 0.f;                                         \
            }                                                                   \
        }                                                                       \
    }

template<int XO32>
__global__ __launch_bounds__(256) void mid_kernel(
    const float* __restrict__ x, const float* __restrict__ emb,
    const float* __restrict__ coef, const float2* __restrict__ V,
    const int* __restrict__ bins,
    float* __restrict__ xo32, unsigned short* __restrict__ xo16)
{
    __shared__ unsigned short M1t[64 * 72];   // basis  [t][k], pad-to-72
    __shared__ unsigned short Yt[128 * 72];   // Ycomb^T [e][k], k: m->re, m+32->im
    __shared__ float cosT[64];
    __shared__ float sinT[64];

    const int blk = blockIdx.x;
    const int b = blk >> 5, n = blk & 31;
    const int tid = threadIdx.x;
    const int wave = tid >> 6, lane = tid & 63, l15 = lane & 15, q = lane >> 4;
    const float C64 = 0.09817477042468103f;

    if (tid < 64) {
        float ang = (float)tid * C64;
        cosT[tid] = __cosf(ang);
        sinT[tid] = __sinf(ang);
    }

    float win16[4][4];
    #pragma unroll
    for (int tt = 0; tt < 4; ++tt)
        #pragma unroll
        for (int i = 0; i < 4; ++i) {
            int t = tt * 16 + q * 4 + i;
            win16[tt][i] = 0.5f - 0.5f * __cosf((float)t * C64);
        }
    float renv[2][4];
    #pragma unroll
    for (int hf = 0; hf < 2; ++hf)
        #pragma unroll
        for (int i = 0; i < 4; ++i) {
            int k = hf * 16 + q * 4 + i;
            float w0 = 0.5f - 0.5f * __cosf((float)k * C64);
            float w1v = 0.5f - 0.5f * __cosf((float)(k + 32) * C64);
            renv[hf][i] = 1.0f / (w0 * w0 + w1v * w1v);
        }
    int ebase[2];
    float emb2[2];
    #pragma unroll
    for (int e2 = 0; e2 < 2; ++e2) {
        ebase[e2] = (wave * 2 + e2) * 16 + l15;
        emb2[e2] = emb[ebase[e2]];
    }

    float roll[2][4][4];
    #pragma unroll
    for (int e2 = 0; e2 < 2; ++e2)
        #pragma unroll
        for (int jj = 0; jj < 4; ++jj)
            #pragma unroll
            for (int i = 0; i < 4; ++i) roll[e2][jj][i] = 0.f;

    const int e1 = tid & 127;
    const int mg = (tid >> 7) << 4;
    const int tM = tid & 63;
    const int kg = wave << 4;
    const size_t bnwb = (size_t)blk * 17;
    const size_t xobase = (size_t)blk << 16;
    const size_t xrow = (size_t)b * 16384 + n;

    __syncthreads();

    for (int w = 0; w < 17; ++w) {
        // ---- stage Y (bf16) ----
        {
            const float4* cf = (const float4*)(coef + ((size_t)(w * 128 + e1)) * 8);
            float4 cA = cf[0];
            float4 cB = cf[1];
            unsigned int rep[8], imp[8];
            #pragma unroll
            for (int j2 = 0; j2 < 8; ++j2) {
                unsigned int rpack = 0, ipack = 0;
                #pragma unroll
                for (int s = 0; s < 2; ++s) {
                    int m = mg + j2 * 2 + s;
                    size_t vb = (bnwb + w) * 32 + m;
                    float2 vm = V[vb];
                    float2 vl = (w > 0) ? V[vb - 32] : make_float2(0.f, 0.f);
                    float2 vp = (w < 16) ? V[vb + 32] : make_float2(0.f, 0.f);
                    float re = cB.z;
                    re = fmaf(vm.x, cA.x, re); re = fmaf(-vm.y, cA.y, re);
                    re = fmaf(vl.x, cA.z, re); re = fmaf(-vl.y, cA.w, re);
                    re = fmaf(vp.x, cB.x, re); re = fmaf(-vp.y, cB.y, re);
                    float im = cB.w;
                    im = fmaf(vm.y, cA.x, im); im = fmaf(vm.x, cA.y, im);
                    im = fmaf(vl.y, cA.z, im); im = fmaf(vl.x, cA.w, im);
                    im = fmaf(vp.y, cB.x, im); im = fmaf(vp.x, cB.y, im);
                    re = fmaxf(re, 0.f);   // relu+softshrink folded (bias pre-shifted)
                    im = fmaxf(im, 0.f);
                    rpack |= (unsigned int)f2bf(re) << (16 * s);
                    ipack |= (unsigned int)f2bf(im) << (16 * s);
                }
                rep[j2] = rpack; imp[j2] = ipack;
            }
            uint4* dr = (uint4*)&Yt[e1 * 72 + mg];
            dr[0] = make_uint4(rep[0], rep[1], rep[2], rep[3]);
            dr[1] = make_uint4(rep[4], rep[5], rep[6], rep[7]);
            uint4* di = (uint4*)&Yt[e1 * 72 + 32 + mg];
            di[0] = make_uint4(imp[0], imp[1], imp[2], imp[3]);
            di[1] = make_uint4(imp[4], imp[5], imp[6], imp[7]);
        }
        // ---- M1 basis (irfft cos/sin, bin scatter, 1/64 scaling) ----
        {
            unsigned int mp[8];
            #pragma unroll
            for (int j2 = 0; j2 < 8; ++j2) {
                unsigned int pk = 0;
                #pragma unroll
                for (int s = 0; s < 2; ++s) {
                    int k = kg + j2 * 2 + s;
                    int m = k & 31;
                    int r = bins[(bnwb + w) * 32 + m];
                    float sc = (r == 0 || r == 32) ? 0.015625f : 0.03125f;
                    int idx = (r * tM) & 63;
                    float val = (k < 32) ? (cosT[idx] * sc) : (-sinT[idx] * sc);
                    pk |= (unsigned int)f2bf(val) << (16 * s);
                }
                mp[j2] = pk;
            }
            uint4* dm = (uint4*)&M1t[tM * 72 + kg];
            dm[0] = make_uint4(mp[0], mp[1], mp[2], mp[3]);
            dm[1] = make_uint4(mp[4], mp[5], mp[6], mp[7]);
        }
        __syncthreads();

        // ---- MFMA: OUT[t][e] = M1[t][k] @ Ycomb[k][e] ----
        v4f acc[4][2];
        #pragma unroll
        for (int tt = 0; tt < 4; ++tt)
            #pragma unroll
            for (int e2 = 0; e2 < 2; ++e2) acc[tt][e2] = (v4f){0.f, 0.f, 0.f, 0.f};
        #pragma unroll
        for (int ks = 0; ks < 2; ++ks) {
            v8s bfr[2];
            #pragma unroll
            for (int e2 = 0; e2 < 2; ++e2)
                bfr[e2] = *(const v8s*)&Yt[ebase[e2] * 72 + ks * 32 + q * 8];
            #pragma unroll
            for (int tt = 0; tt < 4; ++tt) {
                v8s af = *(const v8s*)&M1t[(tt * 16 + l15) * 72 + ks * 32 + q * 8];
                #pragma unroll
                for (int e2 = 0; e2 < 2; ++e2)
                    acc[tt][e2] = __builtin_amdgcn_mfma_f32_16x16x32_bf16(
                        af, bfr[e2], acc[tt][e2], 0, 0, 0);
            }
        }

        // ---- OLA: slot jj = (2w+tt)&3; flush finalized 32 samples ----
        if ((w & 1) == 0) {
            MID_ROLL(0, 1, 2, 3);
            if (w > 0) {
                MID_FLUSH(0, 1);
            } else {
                // chunks 0,1 (abs samples [0,32)) are sliced away by pad-trim:
                // discard, or they contaminate chunks 4,5 (R1 bug, absmax 0.28)
                #pragma unroll
                for (int e2 = 0; e2 < 2; ++e2)
                    #pragma unroll
                    for (int i = 0; i < 4; ++i) {
                        roll[e2][0][i] = 0.f; roll[e2][1][i] = 0.f;
                    }
            }
        } else {
            MID_ROLL(2, 3, 0, 1);
            MID_FLUSH(2, 3);
        }
        __syncthreads();
    }
}

// ---------------------------------------------------------------------------
// Kernel D: FC1 split-K GEMM, error-compensated bf16 (hi/lo).
// AF32: xo is f32 -> A split hi/lo, 3 MFMAs (AhWh + AhWl + AlWh).
// else: xo bf16 -> 2 MFMAs (AWh + AWl).  W always split hi/lo from f32.
// grid (16, KS), block 256. 128x128 tile, BK=32, 16x16x32 bf16 MFMA.
// ---------------------------------------------------------------------------
template<bool AF32>
__global__ __launch_bounds__(256) void gemm_kernel(
    const void* __restrict__ xo_, const float* __restrict__ w1,
    float* __restrict__ hp, int kchunk)
{
    __shared__ unsigned short Ash[128 * 40];
    __shared__ unsigned short Asl[AF32 ? 128 * 40 : 8];
    __shared__ unsigned short Wsh[128 * 40];
    __shared__ unsigned short Wsl[128 * 40];

    const int tid = threadIdx.x;
    const int mt = blockIdx.x >> 2, nt = blockIdx.x & 3;
    const int ks = blockIdx.y;
    const int wave = tid >> 6, lane = tid & 63, l15 = lane & 15, q = lane >> 4;
    const int k0 = ks * kchunk;
    const int iters = kchunk >> 5;

    v4f acc[2][8];
    #pragma unroll
    for (int a = 0; a < 2; ++a)
        #pragma unroll
        for (int c = 0; c < 8; ++c) acc[a][c] = (v4f){0.f, 0.f, 0.f, 0.f};

    const int am = tid >> 1, ah = (tid & 1) << 4;
    const float* ap32 = (const float*)xo_ + (((size_t)(mt * 128 + am)) << 16) + k0 + ah;
    const unsigned short* ap16 =
        (const unsigned short*)xo_ + (((size_t)(mt * 128 + am)) << 16) + k0 + ah;
    const int wn = (tid & 31) << 2, wk = (tid >> 5) << 2;
    const float* wp = w1 + (size_t)(k0 + wk) * 512 + nt * 128 + wn;

    for (int it = 0; it < iters; ++it) {
        float fv[16];
        uint4 a016, a116;
        if (AF32) {
            float4 f0 = *(const float4*)(ap32);
            float4 f1 = *(const float4*)(ap32 + 4);
            float4 f2 = *(const float4*)(ap32 + 8);
            float4 f3 = *(const float4*)(ap32 + 12);
            ap32 += 32;
            fv[0]=f0.x; fv[1]=f0.y; fv[2]=f0.z; fv[3]=f0.w;
            fv[4]=f1.x; fv[5]=f1.y; fv[6]=f1.z; fv[7]=f1.w;
            fv[8]=f2.x; fv[9]=f2.y; fv[10]=f2.z; fv[11]=f2.w;
            fv[12]=f3.x; fv[13]=f3.y; fv[14]=f3.z; fv[15]=f3.w;
        } else {
            a016 = *(const uint4*)ap16;
            a116 = *(const uint4*)(ap16 + 8);
            ap16 += 32;
        }
        float4 r0 = *(const float4*)(wp);
        float4 r1 = *(const float4*)(wp + 512);
        float4 r2 = *(const float4*)(wp + 1024);
        float4 r3 = *(const float4*)(wp + 1536);
        wp += 16384;

        __syncthreads();
        if (AF32) {
            unsigned int hp8[8], lp8[8];
            #pragma unroll
            for (int j = 0; j < 8; ++j) {
                unsigned short h0 = f2bf(fv[2 * j]);
                unsigned short l0 = f2bf(fv[2 * j] - bf2f(h0));
                unsigned short h1 = f2bf(fv[2 * j + 1]);
                unsigned short l1 = f2bf(fv[2 * j + 1] - bf2f(h1));
                hp8[j] = (unsigned int)h0 | ((unsigned int)h1 << 16);
                lp8[j] = (unsigned int)l0 | ((unsigned int)l1 << 16);
            }
            uint4* dh = (uint4*)&Ash[am * 40 + ah];
            dh[0] = make_uint4(hp8[0], hp8[1], hp8[2], hp8[3]);
            dh[1] = make_uint4(hp8[4], hp8[5], hp8[6], hp8[7]);
            uint4* dl = (uint4*)&Asl[am * 40 + ah];
            dl[0] = make_uint4(lp8[0], lp8[1], lp8[2], lp8[3]);
            dl[1] = make_uint4(lp8[4], lp8[5], lp8[6], lp8[7]);
        } else {
            *(uint4*)&Ash[am * 40 + ah] = a016;
            *(uint4*)&Ash[am * 40 + ah + 8] = a116;
        }
        {
            float rr[4][4] = {{r0.x, r0.y, r0.z, r0.w},
                              {r1.x, r1.y, r1.z, r1.w},
                              {r2.x, r2.y, r2.z, r2.w},
                              {r3.x, r3.y, r3.z, r3.w}};
            #pragma unroll
            for (int j = 0; j < 4; ++j) {
                unsigned short h0 = f2bf(rr[0][j]);
                unsigned short l0 = f2bf(rr[0][j] - bf2f(h0));
                unsigned short h1 = f2bf(rr[1][j]);
                unsigned short l1 = f2bf(rr[1][j] - bf2f(h1));
                unsigned short h2 = f2bf(rr[2][j]);
                unsigned short l2 = f2bf(rr[2][j] - bf2f(h2));
                unsigned short h3 = f2bf(rr[3][j]);
                unsigned short l3 = f2bf(rr[3][j] - bf2f(h3));
                *(uint2*)&Wsh[(wn + j) * 40 + wk] = make_uint2(
                    (unsigned int)h0 | ((unsigned int)h1 << 16),
                    (unsigned int)h2 | ((unsigned int)h3 << 16));
                *(uint2*)&Wsl[(wn + j) * 40 + wk] = make_uint2(
                    (unsigned int)l0 | ((unsigned int)l1 << 16),
                    (unsigned int)l2 | ((unsigned int)l3 << 16));
            }
        }
        __syncthreads();

        v8s bh[8], bl[8];
        #pragma unroll
        for (int n8 = 0; n8 < 8; ++n8) {
            bh[n8] = *(const v8s*)&Wsh[(n8 * 16 + l15) * 40 + q * 8];
            bl[n8] = *(const v8s*)&Wsl[(n8 * 16 + l15) * 40 + q * 8];
        }
        #pragma unroll
        for (int m2 = 0; m2 < 2; ++m2) {
            v8s ahf = *(const v8s*)&Ash[(wave * 32 + m2 * 16 + l15) * 40 + q * 8];
            v8s alf;
            if (AF32) alf = *(const v8s*)&Asl[(wave * 32 + m2 * 16 + l15) * 40 + q * 8];
            #pragma unroll
            for (int n8 = 0; n8 < 8; ++n8) {
                acc[m2][n8] = __builtin_amdgcn_mfma_f32_16x16x32_bf16(
                    ahf, bh[n8], acc[m2][n8], 0, 0, 0);
                acc[m2][n8] = __builtin_amdgcn_mfma_f32_16x16x32_bf16(
                    ahf, bl[n8], acc[m2][n8], 0, 0, 0);
                if (AF32)
                    acc[m2][n8] = __builtin_amdgcn_mfma_f32_16x16x32_bf16(
                        alf, bh[n8], acc[m2][n8], 0, 0, 0);
            }
        }
    }

    #pragma unroll
    for (int m2 = 0; m2 < 2; ++m2)
        #pragma unroll
        for (int n8 = 0; n8 < 8; ++n8) {
            int row = mt * 128 + wave * 32 + m2 * 16 + q * 4;
            int col = nt * 128 + n8 * 16 + l15;
            float* dst = hp + ((size_t)ks * 512 + row) * 512 + col;
            #pragma unroll
            for (int i = 0; i < 4; ++i) dst[(size_t)i * 512] = acc[m2][n8][i];
        }
}

// ---------------------------------------------------------------------------
// Kernel E: reduce split-K partials + b1 + leaky_relu, then FC2 + b2.
// ---------------------------------------------------------------------------
__global__ __launch_bounds__(128) void fc2_kernel(
    const float* __restrict__ hp, const float* __restrict__ b1,
    const float* __restrict__ w2, const float* __restrict__ b2,
    float* __restrict__ out, int KS)
{
    __shared__ float hbuf[512];
    const int row = blockIdx.x;
    const int tid = threadIdx.x;
    #pragma unroll
    for (int ii = 0; ii < 4; ++ii) {
        int hid = tid + ii * 128;
        float s = b1[hid];
        for (int k = 0; k < KS; ++k) s += hp[((size_t)k * 512 + row) * 512 + hid];
        hbuf[hid] = (s > 0.f) ? s : 0.01f * s;
    }
    __syncthreads();
    if (tid < 96) {
        float a = b2[tid];
        #pragma unroll 8
        for (int h = 0; h < 512; ++h) a = fmaf(hbuf[h], w2[h * 96 + tid], a);
        int b = row >> 5, n = row & 31;
        out[(size_t)b * 3072 + tid * 32 + n] = a;
    }
}

// ---------------------------------------------------------------------------
extern "C" void kernel_launch(void* const* d_in, const int* in_sizes, int n_in,
                              void* d_out, int out_size, void* d_ws, size_t ws_size,
                              hipStream_t stream) {
    const float* x   = (const float*)d_in[0];
    const float* emb = (const float*)d_in[1];
    const float* Wr  = (const float*)d_in[2];
    const float* Wi  = (const float*)d_in[3];
    const float* Wrl = (const float*)d_in[4];
    const float* Wil = (const float*)d_in[5];
    const float* Wrr = (const float*)d_in[6];
    const float* Wir = (const float*)d_in[7];
    const float* br  = (const float*)d_in[8];
    const float* bi  = (const float*)d_in[9];
    const float* w1  = (const float*)d_in[10];
    const float* b1  = (const float*)d_in[11];
    const float* w2  = (const float*)d_in[12];
    const float* b2  = (const float*)d_in[13];

    char* ws = (char*)d_ws;
    float* coef = (float*)(ws + OFF_COEF);
    float2* V   = (float2*)(ws + OFF_V);
    int* bins   = (int*)(ws + OFF_BINS);
    void* xop   = (void*)(ws + OFF_XO);

    const size_t XO32_BYTES = 512ull * 65536 * 4;   // 134 MB
    const size_t XO16_BYTES = 512ull * 65536 * 2;   // 67 MB
    const size_t HP_UNIT = 512ull * 512 * 4;        // 1 MB per split-K slice

    int KS = 0; bool f32path = false; size_t off_hp = 0;
    for (int k = 32; k >= 4; k >>= 1)
        if (OFF_XO + XO32_BYTES + (size_t)k * HP_UNIT <= ws_size) {
            KS = k; f32path = true; off_hp = OFF_XO + XO32_BYTES; break;
        }
    if (!KS)
        for (int k = 32; k >= 2; k >>= 1)
            if (OFF_XO + XO16_BYTES + (size_t)k * HP_UNIT <= ws_size) {
                KS = k; off_hp = OFF_XO + XO16_BYTES; break;
            }
    if (!KS) { KS = 2; off_hp = OFF_XO + XO16_BYTES; }  // last resort
    int kchunk = 65536 / KS;
    float* hpp = (float*)(ws + off_hp);

    coef_kernel<<<dim3(17, 8), dim3(128), 0, stream>>>(
        emb, Wr, Wi, Wrl, Wil, Wrr, Wir, br, bi, coef);
    stft_kernel<<<dim3(512), dim3(256), 0, stream>>>(x, V, bins);
    if (f32path) {
        mid_kernel<1><<<dim3(512), dim3(256), 0, stream>>>(
            x, emb, coef, V, bins, (float*)xop, nullptr);
        gemm_kernel<true><<<dim3(16, KS), dim3(256), 0, stream>>>(
            xop, w1, hpp, kchunk);
    } else {
        mid_kernel<0><<<dim3(512), dim3(256), 0, stream>>>(
            x, emb, coef, V, bins, nullptr, (unsigned short*)xop);
        gemm_kernel<false><<<dim3(16, KS), dim3(256), 0, stream>>>(
            xop, w1, hpp, kchunk);
    }
    fc2_kernel<<<dim3(512), dim3(128), 0, stream>>>(hpp, b1, w2, b2, (float*)d_out, KS);
}

// Round 3
// 527.391 us; speedup vs baseline: 1.0216x; 1.0216x over previous
//
#include <hip/hip_runtime.h>
#include <hip/hip_bf16.h>

// B=16, SEQ=512, NF=32, E=128, HID=512, PRED=96, N_FFT=64, HOP=32, TOPM=32
// W=17, F=33, LAM=0.01
#define LAM 0.01f

typedef __attribute__((ext_vector_type(8))) short v8s;
typedef __attribute__((ext_vector_type(4))) float v4f;

static __device__ __forceinline__ unsigned short f2bf(float f) {
    union { float f; unsigned int u; } v; v.f = f;
    unsigned int u = v.u;
    u += 0x7fffu + ((u >> 16) & 1u);   // RNE
    return (unsigned short)(u >> 16);
}

// async global->LDS DMA, 16 B per lane, lands at ldsbase + lane*16
static __device__ __forceinline__ void async16(const void* g, void* l) {
    __builtin_amdgcn_global_load_lds(
        (const __attribute__((address_space(1))) unsigned int*)g,
        (__attribute__((address_space(3))) unsigned int*)l, 16, 0, 0);
}

// Workspace layout (bytes)
#define OFF_COEF 0ull
#define OFF_V    69632ull
#define OFF_BINS 2297856ull
#define OFF_AIMG 3411968ull                     // 512*65536 bf16 swizzled = 67,108,864
#define OFF_W1P  70520832ull                    // 65536*512 bf16 swizzled = 67,108,864
#define OFF_HP   137629696ull                   // KS * 1 MiB f32

// ---------------------------------------------------------------------------
// Kernel A: coef[w][e][j]: j=0..5 -> emb . Wj[w,:,e]; j=6 -> br-LAM; j=7 -> bi-LAM
// ---------------------------------------------------------------------------
__global__ __launch_bounds__(128) void coef_kernel(
    const float* __restrict__ emb,
    const float* __restrict__ Wr, const float* __restrict__ Wi,
    const float* __restrict__ Wrl, const float* __restrict__ Wil,
    const float* __restrict__ Wrr, const float* __restrict__ Wir,
    const float* __restrict__ br, const float* __restrict__ bi,
    float* __restrict__ coef)
{
    int w = blockIdx.x, j = blockIdx.y, e = threadIdx.x;
    float out;
    if (j < 6) {
        const float* Wj;
        switch (j) {
            case 0: Wj = Wr; break; case 1: Wj = Wi; break;
            case 2: Wj = Wrl; break; case 3: Wj = Wil; break;
            case 4: Wj = Wrr; break; default: Wj = Wir; break;
        }
        const float* p = Wj + (size_t)w * 16384 + e;
        float acc = 0.f;
        #pragma unroll 8
        for (int ep = 0; ep < 128; ++ep) acc = fmaf(emb[ep], p[ep * 128], acc);
        out = acc;
    } else if (j == 6) {
        out = br[w * 128 + e] - LAM;
    } else {
        out = bi[w * 128 + e] - LAM;
    }
    coef[((size_t)(w * 128 + e)) * 8 + j] = out;
}

// ---------------------------------------------------------------------------
// Kernel B: per (b,n): windowed 64-pt DFT, 17x33 bins, rank |S|, store top-32.
// ---------------------------------------------------------------------------
__global__ __launch_bounds__(256) void stft_kernel(
    const float* __restrict__ x, float2* __restrict__ V, int* __restrict__ bins)
{
    __shared__ float sig[576];
    __shared__ float winT[64];
    __shared__ float2 tw[64];
    __shared__ float2 Sbuf[17 * 33];
    __shared__ float absb[17 * 33];

    const int blk = blockIdx.x;
    const int b = blk >> 5, n = blk & 31;
    const int tid = threadIdx.x;
    const float C64 = 0.09817477042468103f; // 2*pi/64

    if (tid < 64) {
        float ang = (float)tid * C64;
        winT[tid] = 0.5f - 0.5f * cosf(ang);
        tw[tid] = make_float2(cosf(ang), sinf(ang));   // accurate libm: top-k tie safety
    }
    for (int l = tid; l < 576; l += 256) {
        int t = (l < 32) ? (32 - l) : ((l < 544) ? (l - 32) : (1054 - l)); // reflect
        sig[l] = x[(size_t)b * 16384 + t * 32 + n];
    }
    __syncthreads();

    for (int task = tid; task < 561; task += 256) {
        int w = task / 33, f = task - w * 33;
        float sr = 0.f, si = 0.f;
        int base = w * 32;
        for (int t = 0; t < 64; ++t) {
            float sw = sig[base + t] * winT[t];
            float2 cs = tw[(f * t) & 63];
            sr = fmaf(sw, cs.x, sr);
            si = fmaf(sw, -cs.y, si);
        }
        Sbuf[task] = make_float2(sr, si);
        absb[task] = sqrtf(fmaf(sr, sr, si * si));
    }
    __syncthreads();

    for (int task = tid; task < 561; task += 256) {
        int w = task / 33, f = task - w * 33;
        float a = absb[task];
        int base = w * 33, rank = 0;
        for (int j = 0; j < 33; ++j) {
            float aj = absb[base + j];
            rank += (aj > a) || (aj == a && j < f);   // stable
        }
        if (rank < 32) {
            size_t o = ((size_t)blk * 17 + w) * 32 + rank;
            V[o] = Sbuf[task];
            bins[o] = f;
        }
    }
}

// ---------------------------------------------------------------------------
// Kernel W-cvt: w1 f32 -> bf16 swizzled DMA image.
// Image: [nt(4)][kb(2048)][n'(128)][32k], row = 64 B, chunk c_log stored at
// position c_log ^ ((n'>>2)&3). grid (2048, 4), block 256.
// ---------------------------------------------------------------------------
__global__ __launch_bounds__(256) void cvt_kernel(
    const float* __restrict__ w1, unsigned short* __restrict__ w1p)
{
    __shared__ float T[32][132];
    const int kb = blockIdx.x, nt = blockIdx.y;
    const int tid = threadIdx.x;

    #pragma unroll
    for (int p = 0; p < 4; ++p) {
        int r = (tid >> 5) + p * 8;
        int c = (tid & 31) * 4;
        float4 v = *(const float4*)&w1[((size_t)(kb * 32 + r)) * 512 + nt * 128 + c];
        T[r][c] = v.x; T[r][c + 1] = v.y; T[r][c + 2] = v.z; T[r][c + 3] = v.w;
    }
    __syncthreads();

    unsigned short* dst = w1p + ((size_t)nt * 2048 + kb) * 4096;
    #pragma unroll
    for (int p = 0; p < 2; ++p) {
        int pos = tid + 256 * p;            // 16-B chunk index, image-linear
        int np = pos >> 2, cs = pos & 3;
        int clog = cs ^ ((np >> 2) & 3);
        unsigned int pk[4];
        #pragma unroll
        for (int j2 = 0; j2 < 4; ++j2) {
            unsigned short lo = f2bf(T[clog * 8 + j2 * 2][np]);
            unsigned short hi = f2bf(T[clog * 8 + j2 * 2 + 1][np]);
            pk[j2] = (unsigned int)lo | ((unsigned int)hi << 16);
        }
        *(uint4*)&dst[pos * 8] = make_uint4(pk[0], pk[1], pk[2], pk[3]);
    }
}

// ---------------------------------------------------------------------------
// Kernel C: mid — y bf16; irfft basis; MFMA 64x128; hann; register OLA; /env;
// + x*emb; write A-image bf16 swizzled: [mt(4)][kb(2048)][m'(128)][32k].
// grid 512, block 256.
// ---------------------------------------------------------------------------
#define MID_ROLL(J0, J1, J2, J3)                                                \
    {                                                                           \
        _Pragma("unroll") for (int e2 = 0; e2 < 2; ++e2)                        \
        _Pragma("unroll") for (int i = 0; i < 4; ++i) {                         \
            roll[e2][J0][i] = fmaf(acc[0][e2][i], win16[0][i], roll[e2][J0][i]);\
            roll[e2][J1][i] = fmaf(acc[1][e2][i], win16[1][i], roll[e2][J1][i]);\
            roll[e2][J2][i] = fmaf(acc[2][e2][i], win16[2][i], roll[e2][J2][i]);\
            roll[e2][J3][i] = fmaf(acc[3][e2][i], win16[3][i], roll[e2][J3][i]);\
        }                                                                       \
    }

#define MID_FLUSH(JJA, JJB)                                                     \
    {                                                                           \
        _Pragma("unroll") for (int i = 0; i < 4; ++i) {                         \
            int tp = 32 * (w - 1) + q * 4 + i;                                  \
            float xb = x[xrow + tp * 32];                                       \
            _Pragma("unroll") for (int e2 = 0; e2 < 2; ++e2) {                  \
                float val = fmaf(roll[e2][JJA][i], renv[0][i], xb * emb2[e2]);  \
                Aimg[cbase[e2] + (size_t)tp * 16384] = f2bf(val);               \
                roll[e2][JJA][i] = 0.f;                                         \
            }                                                                   \
            int tp2 = tp + 16;                                                  \
            float xb2 = x[xrow + tp2 * 32];                                     \
            _Pragma("unroll") for (int e2 = 0; e2 < 2; ++e2) {                  \
                float val = fmaf(roll[e2][JJB][i], renv[1][i], xb2 * emb2[e2]); \
                Aimg[cbase[e2] + (size_t)tp2 * 16384] = f2bf(val);              \
                roll[e2][JJB][i] = 0.f;                                         \
            }                                                                   \
        }                                                                       \
    }

__global__ __launch_bounds__(256) void mid_kernel(
    const float* __restrict__ x, const float* __restrict__ emb,
    const float* __restrict__ coef, const float2* __restrict__ V,
    const int* __restrict__ bins, unsigned short* __restrict__ Aimg)
{
    __shared__ unsigned short M1t[64 * 72];
    __shared__ unsigned short Yt[128 * 72];
    __shared__ float cosT[64];
    __shared__ float sinT[64];

    const int blk = blockIdx.x;
    const int b = blk >> 5, n = blk & 31;
    const int tid = threadIdx.x;
    const int wave = tid >> 6, lane = tid & 63, l15 = lane & 15, q = lane >> 4;
    const float C64 = 0.09817477042468103f;

    if (tid < 64) {
        float ang = (float)tid * C64;
        cosT[tid] = __cosf(ang);
        sinT[tid] = __sinf(ang);
    }

    float win16[4][4];
    #pragma unroll
    for (int tt = 0; tt < 4; ++tt)
        #pragma unroll
        for (int i = 0; i < 4; ++i) {
            int t = tt * 16 + q * 4 + i;
            win16[tt][i] = 0.5f - 0.5f * __cosf((float)t * C64);
        }
    float renv[2][4];
    #pragma unroll
    for (int hf = 0; hf < 2; ++hf)
        #pragma unroll
        for (int i = 0; i < 4; ++i) {
            int k = hf * 16 + q * 4 + i;
            float w0 = 0.5f - 0.5f * __cosf((float)k * C64);
            float w1v = 0.5f - 0.5f * __cosf((float)(k + 32) * C64);
            renv[hf][i] = 1.0f / (w0 * w0 + w1v * w1v);
        }
    int ebase[2];
    float emb2[2];
    size_t cbase[2];
    const int mt = blk >> 7, mp = blk & 127, s = (mp >> 2) & 3;
    #pragma unroll
    for (int e2 = 0; e2 < 2; ++e2) {
        ebase[e2] = (wave * 2 + e2) * 16 + l15;
        emb2[e2] = emb[ebase[e2]];
        int e = ebase[e2];
        int echunk = e >> 5, clog = (e >> 3) & 3, cs = clog ^ s, el = e & 7;
        cbase[e2] = ((size_t)mt * 2048 + echunk) * 4096 + mp * 32 + cs * 8 + el;
    }

    float roll[2][4][4];
    #pragma unroll
    for (int e2 = 0; e2 < 2; ++e2)
        #pragma unroll
        for (int jj = 0; jj < 4; ++jj)
            #pragma unroll
            for (int i = 0; i < 4; ++i) roll[e2][jj][i] = 0.f;

    const int e1 = tid & 127;
    const int mg = (tid >> 7) << 4;
    const int tM = tid & 63;
    const int kg = wave << 4;
    const size_t bnwb = (size_t)blk * 17;
    const size_t xrow = (size_t)b * 16384 + n;

    __syncthreads();

    for (int w = 0; w < 17; ++w) {
        // ---- Y (bf16) ----
        {
            const float4* cf = (const float4*)(coef + ((size_t)(w * 128 + e1)) * 8);
            float4 cA = cf[0];
            float4 cB = cf[1];
            unsigned int rep[8], imp[8];
            #pragma unroll
            for (int j2 = 0; j2 < 8; ++j2) {
                unsigned int rpack = 0, ipack = 0;
                #pragma unroll
                for (int sdx = 0; sdx < 2; ++sdx) {
                    int m = mg + j2 * 2 + sdx;
                    size_t vb = (bnwb + w) * 32 + m;
                    float2 vm = V[vb];
                    float2 vl = (w > 0) ? V[vb - 32] : make_float2(0.f, 0.f);
                    float2 vp = (w < 16) ? V[vb + 32] : make_float2(0.f, 0.f);
                    float re = cB.z;
                    re = fmaf(vm.x, cA.x, re); re = fmaf(-vm.y, cA.y, re);
                    re = fmaf(vl.x, cA.z, re); re = fmaf(-vl.y, cA.w, re);
                    re = fmaf(vp.x, cB.x, re); re = fmaf(-vp.y, cB.y, re);
                    float im = cB.w;
                    im = fmaf(vm.y, cA.x, im); im = fmaf(vm.x, cA.y, im);
                    im = fmaf(vl.y, cA.z, im); im = fmaf(vl.x, cA.w, im);
                    im = fmaf(vp.y, cB.x, im); im = fmaf(vp.x, cB.y, im);
                    re = fmaxf(re, 0.f);
                    im = fmaxf(im, 0.f);
                    rpack |= (unsigned int)f2bf(re) << (16 * sdx);
                    ipack |= (unsigned int)f2bf(im) << (16 * sdx);
                }
                rep[j2] = rpack; imp[j2] = ipack;
            }
            uint4* dr = (uint4*)&Yt[e1 * 72 + mg];
            dr[0] = make_uint4(rep[0], rep[1], rep[2], rep[3]);
            dr[1] = make_uint4(rep[4], rep[5], rep[6], rep[7]);
            uint4* di = (uint4*)&Yt[e1 * 72 + 32 + mg];
            di[0] = make_uint4(imp[0], imp[1], imp[2], imp[3]);
            di[1] = make_uint4(imp[4], imp[5], imp[6], imp[7]);
        }
        // ---- M1 basis ----
        {
            unsigned int mpk[8];
            #pragma unroll
            for (int j2 = 0; j2 < 8; ++j2) {
                unsigned int pk = 0;
                #pragma unroll
                for (int sdx = 0; sdx < 2; ++sdx) {
                    int k = kg + j2 * 2 + sdx;
                    int m = k & 31;
                    int r = bins[(bnwb + w) * 32 + m];
                    float sc = (r == 0 || r == 32) ? 0.015625f : 0.03125f;
                    int idx = (r * tM) & 63;
                    float val = (k < 32) ? (cosT[idx] * sc) : (-sinT[idx] * sc);
                    pk |= (unsigned int)f2bf(val) << (16 * sdx);
                }
                mpk[j2] = pk;
            }
            uint4* dm = (uint4*)&M1t[tM * 72 + kg];
            dm[0] = make_uint4(mpk[0], mpk[1], mpk[2], mpk[3]);
            dm[1] = make_uint4(mpk[4], mpk[5], mpk[6], mpk[7]);
        }
        __syncthreads();

        // ---- MFMA: OUT[t][e] = M1[t][k] @ Ycomb[k][e] ----
        v4f acc[4][2];
        #pragma unroll
        for (int tt = 0; tt < 4; ++tt)
            #pragma unroll
            for (int e2 = 0; e2 < 2; ++e2) acc[tt][e2] = (v4f){0.f, 0.f, 0.f, 0.f};
        #pragma unroll
        for (int ks = 0; ks < 2; ++ks) {
            v8s bfr[2];
            #pragma unroll
            for (int e2 = 0; e2 < 2; ++e2)
                bfr[e2] = *(const v8s*)&Yt[ebase[e2] * 72 + ks * 32 + q * 8];
            #pragma unroll
            for (int tt = 0; tt < 4; ++tt) {
                v8s af = *(const v8s*)&M1t[(tt * 16 + l15) * 72 + ks * 32 + q * 8];
                #pragma unroll
                for (int e2 = 0; e2 < 2; ++e2)
                    acc[tt][e2] = __builtin_amdgcn_mfma_f32_16x16x32_bf16(
                        af, bfr[e2], acc[tt][e2], 0, 0, 0);
            }
        }

        // ---- OLA ----
        if ((w & 1) == 0) {
            MID_ROLL(0, 1, 2, 3);
            if (w > 0) {
                MID_FLUSH(0, 1);
            } else {
                #pragma unroll
                for (int e2 = 0; e2 < 2; ++e2)
                    #pragma unroll
                    for (int i = 0; i < 4; ++i) {
                        roll[e2][0][i] = 0.f; roll[e2][1][i] = 0.f;
                    }
            }
        } else {
            MID_ROLL(2, 3, 0, 1);
            MID_FLUSH(2, 3);
        }
        __syncthreads();
    }
}

// ---------------------------------------------------------------------------
// Kernel D: FC1 split-K GEMM, single-plane bf16, DMA-staged swizzled tiles.
// grid (16, KS), block 256 (2x2 waves of 64x64). 128x128 tile, BK=32.
// ---------------------------------------------------------------------------
__global__ __launch_bounds__(256) void gemm_kernel(
    const unsigned short* __restrict__ Aimg, const unsigned short* __restrict__ w1p,
    float* __restrict__ hp, int iters)
{
    __shared__ unsigned short As[2][4096];
    __shared__ unsigned short Bs[2][4096];

    const int tid = threadIdx.x;
    const int mt = blockIdx.x >> 2, nt = blockIdx.x & 3;
    const int ks = blockIdx.y;
    const int wave = tid >> 6, lane = tid & 63;
    const int l15 = lane & 15, q = lane >> 4;
    const int wm = wave >> 1, wn = wave & 1;
    const int kb0 = ks * iters;

    const unsigned short* Ab = Aimg + ((size_t)mt * 2048 + kb0) * 4096;
    const unsigned short* Bb = w1p + ((size_t)nt * 2048 + kb0) * 4096;

    const int isB = wave >> 1;
    const int half = wave & 1;
    const int dmaoff = half * 2048 + lane * 8;   // elements

    v4f acc[4][4];
    #pragma unroll
    for (int mf = 0; mf < 4; ++mf)
        #pragma unroll
        for (int nf = 0; nf < 4; ++nf) acc[mf][nf] = (v4f){0.f, 0.f, 0.f, 0.f};

    // prefetch iter 0
    {
        const unsigned short* src = (isB ? Bb : Ab) + dmaoff;
        unsigned short* dst = (isB ? Bs[0] : As[0]) + dmaoff;
        #pragma unroll
        for (int j = 0; j < 4; ++j) async16(src + j * 512, dst + j * 512);
    }

    const int ca = (q ^ ((l15 >> 2) & 3)) * 8;   // swizzled chunk (elements)
    const int rA = (wm * 64 + l15) * 32 + ca;
    const int rB = (wn * 64 + l15) * 32 + ca;

    for (int it = 0; it < iters; ++it) {
        __syncthreads();   // DMA for cur complete; prev buffer free
        if (it + 1 < iters) {
            const unsigned short* src =
                (isB ? Bb : Ab) + (size_t)(it + 1) * 4096 + dmaoff;
            unsigned short* dst = (isB ? Bs[(it + 1) & 1] : As[(it + 1) & 1]) + dmaoff;
            #pragma unroll
            for (int j = 0; j < 4; ++j) async16(src + j * 512, dst + j * 512);
        }
        const int cur = it & 1;
        v8s af[4], bf[4];
        #pragma unroll
        for (int f = 0; f < 4; ++f) {
            af[f] = *(const v8s*)&As[cur][rA + f * 512];   // f*16 rows * 32
            bf[f] = *(const v8s*)&Bs[cur][rB + f * 512];
        }
        #pragma unroll
        for (int mf = 0; mf < 4; ++mf)
            #pragma unroll
            for (int nf = 0; nf < 4; ++nf)
                acc[mf][nf] = __builtin_amdgcn_mfma_f32_16x16x32_bf16(
                    af[mf], bf[nf], acc[mf][nf], 0, 0, 0);
    }

    #pragma unroll
    for (int mf = 0; mf < 4; ++mf)
        #pragma unroll
        for (int nf = 0; nf < 4; ++nf) {
            int row = mt * 128 + wm * 64 + mf * 16 + q * 4;
            int col = nt * 128 + wn * 64 + nf * 16 + l15;
            float* dst = hp + ((size_t)ks * 512 + row) * 512 + col;
            #pragma unroll
            for (int i = 0; i < 4; ++i) dst[(size_t)i * 512] = acc[mf][nf][i];
        }
}

// ---------------------------------------------------------------------------
// Kernel E: reduce split-K + b1 + leaky, FC2 + b2, out[b][p][n].
// ---------------------------------------------------------------------------
__global__ __launch_bounds__(128) void fc2_kernel(
    const float* __restrict__ hp, const float* __restrict__ b1,
    const float* __restrict__ w2, const float* __restrict__ b2,
    float* __restrict__ out, int KS)
{
    __shared__ float hbuf[512];
    const int row = blockIdx.x;
    const int tid = threadIdx.x;
    #pragma unroll
    for (int ii = 0; ii < 4; ++ii) {
        int hid = tid + ii * 128;
        float s = b1[hid];
        for (int k = 0; k < KS; ++k) s += hp[((size_t)k * 512 + row) * 512 + hid];
        hbuf[hid] = (s > 0.f) ? s : 0.01f * s;
    }
    __syncthreads();
    if (tid < 96) {
        float a = b2[tid];
        #pragma unroll 8
        for (int h = 0; h < 512; ++h) a = fmaf(hbuf[h], w2[h * 96 + tid], a);
        int b = row >> 5, n = row & 31;
        out[(size_t)b * 3072 + tid * 32 + n] = a;
    }
}

// ---------------------------------------------------------------------------
extern "C" void kernel_launch(void* const* d_in, const int* in_sizes, int n_in,
                              void* d_out, int out_size, void* d_ws, size_t ws_size,
                              hipStream_t stream) {
    const float* x   = (const float*)d_in[0];
    const float* emb = (const float*)d_in[1];
    const float* Wr  = (const float*)d_in[2];
    const float* Wi  = (const float*)d_in[3];
    const float* Wrl = (const float*)d_in[4];
    const float* Wil = (const float*)d_in[5];
    const float* Wrr = (const float*)d_in[6];
    const float* Wir = (const float*)d_in[7];
    const float* br  = (const float*)d_in[8];
    const float* bi  = (const float*)d_in[9];
    const float* w1  = (const float*)d_in[10];
    const float* b1  = (const float*)d_in[11];
    const float* w2  = (const float*)d_in[12];
    const float* b2  = (const float*)d_in[13];

    char* ws = (char*)d_ws;
    float* coef          = (float*)(ws + OFF_COEF);
    float2* V            = (float2*)(ws + OFF_V);
    int* bins            = (int*)(ws + OFF_BINS);
    unsigned short* Aimg = (unsigned short*)(ws + OFF_AIMG);
    unsigned short* w1p  = (unsigned short*)(ws + OFF_W1P);
    float* hpp           = (float*)(ws + OFF_HP);

    // KS=64 -> 204.7 MB ws; KS=32 -> 171.2 MB (guaranteed: R2 fit this exactly)
    int KS = (ws_size >= OFF_HP + 64ull * 1048576) ? 64 : 32;
    int iters = 2048 / KS;   // kb per block

    coef_kernel<<<dim3(17, 8), dim3(128), 0, stream>>>(
        emb, Wr, Wi, Wrl, Wil, Wrr, Wir, br, bi, coef);
    cvt_kernel<<<dim3(2048, 4), dim3(256), 0, stream>>>(w1, w1p);
    stft_kernel<<<dim3(512), dim3(256), 0, stream>>>(x, V, bins);
    mid_kernel<<<dim3(512), dim3(256), 0, stream>>>(x, emb, coef, V, bins, Aimg);
    gemm_kernel<<<dim3(16, KS), dim3(256), 0, stream>>>(Aimg, w1p, hpp, iters);
    fc2_kernel<<<dim3(512), dim3(128), 0, stream>>>(hpp, b1, w2, b2, (float*)d_out, KS);
}

// Round 4
// 472.902 us; speedup vs baseline: 1.1393x; 1.1152x over previous
//
#include <hip/hip_runtime.h>
#include <hip/hip_bf16.h>

// B=16, SEQ=512, NF=32, E=128, HID=512, PRED=96, N_FFT=64, HOP=32, TOPM=32
// W=17, F=33, LAM=0.01
#define LAM 0.01f

typedef __attribute__((ext_vector_type(8))) short v8s;
typedef __attribute__((ext_vector_type(4))) float v4f;

static __device__ __forceinline__ unsigned short f2bf(float f) {
    union { float f; unsigned int u; } v; v.f = f;
    unsigned int u = v.u;
    u += 0x7fffu + ((u >> 16) & 1u);   // RNE
    return (unsigned short)(u >> 16);
}
static __device__ __forceinline__ float bf2f(unsigned short h) {
    union { unsigned int u; float f; } c; c.u = ((unsigned int)h) << 16;
    return c.f;
}

// async global->LDS DMA, 16 B/lane; lds base MUST be wave-uniform, lane i
// lands at base + i*16 (m104/m108 semantics).
static __device__ __forceinline__ void async16(const void* g, void* l) {
    __builtin_amdgcn_global_load_lds(
        (const __attribute__((address_space(1))) unsigned int*)g,
        (__attribute__((address_space(3))) unsigned int*)l, 16, 0, 0);
}

// Workspace layout (bytes)
#define OFF_COEF 0ull
#define OFF_V    69632ull
#define OFF_BINS 2297856ull
#define OFF_AIMG 3411968ull                     // 512*65536 bf16 swizzled = 67,108,864
#define OFF_W1P  70520832ull                    // 65536*512 bf16 swizzled = 67,108,864
#define OFF_HP   137629696ull                   // KS*512*512*sizeof(hp_t)

// ---------------------------------------------------------------------------
// Kernel A: coef[w][e][j]: j=0..5 -> emb . Wj[w,:,e]; j=6 -> br-LAM; j=7 -> bi-LAM
// ---------------------------------------------------------------------------
__global__ __launch_bounds__(128) void coef_kernel(
    const float* __restrict__ emb,
    const float* __restrict__ Wr, const float* __restrict__ Wi,
    const float* __restrict__ Wrl, const float* __restrict__ Wil,
    const float* __restrict__ Wrr, const float* __restrict__ Wir,
    const float* __restrict__ br, const float* __restrict__ bi,
    float* __restrict__ coef)
{
    int w = blockIdx.x, j = blockIdx.y, e = threadIdx.x;
    float out;
    if (j < 6) {
        const float* Wj;
        switch (j) {
            case 0: Wj = Wr; break; case 1: Wj = Wi; break;
            case 2: Wj = Wrl; break; case 3: Wj = Wil; break;
            case 4: Wj = Wrr; break; default: Wj = Wir; break;
        }
        const float* p = Wj + (size_t)w * 16384 + e;
        float acc = 0.f;
        #pragma unroll 8
        for (int ep = 0; ep < 128; ++ep) acc = fmaf(emb[ep], p[ep * 128], acc);
        out = acc;
    } else if (j == 6) {
        out = br[w * 128 + e] - LAM;
    } else {
        out = bi[w * 128 + e] - LAM;
    }
    coef[((size_t)(w * 128 + e)) * 8 + j] = out;
}

// ---------------------------------------------------------------------------
// Kernel B: per (b,n): windowed 64-pt DFT, 17x33 bins, rank |S|, store top-32.
// ---------------------------------------------------------------------------
__global__ __launch_bounds__(256) void stft_kernel(
    const float* __restrict__ x, float2* __restrict__ V, int* __restrict__ bins)
{
    __shared__ float sig[576];
    __shared__ float winT[64];
    __shared__ float2 tw[64];
    __shared__ float2 Sbuf[17 * 33];
    __shared__ float absb[17 * 33];

    const int blk = blockIdx.x;
    const int b = blk >> 5, n = blk & 31;
    const int tid = threadIdx.x;
    const float C64 = 0.09817477042468103f; // 2*pi/64

    if (tid < 64) {
        float ang = (float)tid * C64;
        winT[tid] = 0.5f - 0.5f * cosf(ang);
        tw[tid] = make_float2(cosf(ang), sinf(ang));   // accurate libm: top-k tie safety
    }
    for (int l = tid; l < 576; l += 256) {
        int t = (l < 32) ? (32 - l) : ((l < 544) ? (l - 32) : (1054 - l)); // reflect
        sig[l] = x[(size_t)b * 16384 + t * 32 + n];
    }
    __syncthreads();

    for (int task = tid; task < 561; task += 256) {
        int w = task / 33, f = task - w * 33;
        float sr = 0.f, si = 0.f;
        int base = w * 32;
        for (int t = 0; t < 64; ++t) {
            float sw = sig[base + t] * winT[t];
            float2 cs = tw[(f * t) & 63];
            sr = fmaf(sw, cs.x, sr);
            si = fmaf(sw, -cs.y, si);
        }
        Sbuf[task] = make_float2(sr, si);
        absb[task] = sqrtf(fmaf(sr, sr, si * si));
    }
    __syncthreads();

    for (int task = tid; task < 561; task += 256) {
        int w = task / 33, f = task - w * 33;
        float a = absb[task];
        int base = w * 33, rank = 0;
        for (int j = 0; j < 33; ++j) {
            float aj = absb[base + j];
            rank += (aj > a) || (aj == a && j < f);   // stable
        }
        if (rank < 32) {
            size_t o = ((size_t)blk * 17 + w) * 32 + rank;
            V[o] = Sbuf[task];
            bins[o] = f;
        }
    }
}

// ---------------------------------------------------------------------------
// Kernel W-cvt: w1 f32 -> bf16 swizzled DMA image.
// Image: [nt(4)][kb(2048)][n'(128)][32k]; chunk c_log at pos c_log^((n'>>2)&3).
// ---------------------------------------------------------------------------
__global__ __launch_bounds__(256) void cvt_kernel(
    const float* __restrict__ w1, unsigned short* __restrict__ w1p)
{
    __shared__ float T[32][132];
    const int kb = blockIdx.x, nt = blockIdx.y;
    const int tid = threadIdx.x;

    #pragma unroll
    for (int p = 0; p < 4; ++p) {
        int r = (tid >> 5) + p * 8;
        int c = (tid & 31) * 4;
        float4 v = *(const float4*)&w1[((size_t)(kb * 32 + r)) * 512 + nt * 128 + c];
        T[r][c] = v.x; T[r][c + 1] = v.y; T[r][c + 2] = v.z; T[r][c + 3] = v.w;
    }
    __syncthreads();

    unsigned short* dst = w1p + ((size_t)nt * 2048 + kb) * 4096;
    #pragma unroll
    for (int p = 0; p < 2; ++p) {
        int pos = tid + 256 * p;            // 16-B chunk index
        int np = pos >> 2, cs = pos & 3;
        int clog = cs ^ ((np >> 2) & 3);
        unsigned int pk[4];
        #pragma unroll
        for (int j2 = 0; j2 < 4; ++j2) {
            unsigned short lo = f2bf(T[clog * 8 + j2 * 2][np]);
            unsigned short hi = f2bf(T[clog * 8 + j2 * 2 + 1][np]);
            pk[j2] = (unsigned int)lo | ((unsigned int)hi << 16);
        }
        *(uint4*)&dst[pos * 8] = make_uint4(pk[0], pk[1], pk[2], pk[3]);
    }
}

// ---------------------------------------------------------------------------
// Kernel C: mid — all per-(b,n) inputs (V, bins, x-row) preloaded to LDS;
// y bf16; irfft basis; MFMA 64x128; hann; register OLA; /env; + x*emb;
// write A-image bf16 swizzled [mt(4)][kb(2048)][m'(128)][32k]. grid 512, 256 thr.
// ---------------------------------------------------------------------------
#define MID_ROLL(J0, J1, J2, J3)                                                \
    {                                                                           \
        _Pragma("unroll") for (int e2 = 0; e2 < 2; ++e2)                        \
        _Pragma("unroll") for (int i = 0; i < 4; ++i) {                         \
            roll[e2][J0][i] = fmaf(acc[0][e2][i], win16[0][i], roll[e2][J0][i]);\
            roll[e2][J1][i] = fmaf(acc[1][e2][i], win16[1][i], roll[e2][J1][i]);\
            roll[e2][J2][i] = fmaf(acc[2][e2][i], win16[2][i], roll[e2][J2][i]);\
            roll[e2][J3][i] = fmaf(acc[3][e2][i], win16[3][i], roll[e2][J3][i]);\
        }                                                                       \
    }

#define MID_FLUSH(JJA, JJB)                                                     \
    {                                                                           \
        _Pragma("unroll") for (int i = 0; i < 4; ++i) {                         \
            int tp = 32 * (w - 1) + q * 4 + i;                                  \
            float xb = xs[tp];                                                  \
            _Pragma("unroll") for (int e2 = 0; e2 < 2; ++e2) {                  \
                float val = fmaf(roll[e2][JJA][i], renv[0][i], xb * emb2[e2]);  \
                Aimg[cbase[e2] + (size_t)tp * 16384] = f2bf(val);               \
                roll[e2][JJA][i] = 0.f;                                         \
            }                                                                   \
            int tp2 = tp + 16;                                                  \
            float xb2 = xs[tp2];                                                \
            _Pragma("unroll") for (int e2 = 0; e2 < 2; ++e2) {                  \
                float val = fmaf(roll[e2][JJB][i], renv[1][i], xb2 * emb2[e2]); \
                Aimg[cbase[e2] + (size_t)tp2 * 16384] = f2bf(val);              \
                roll[e2][JJB][i] = 0.f;                                         \
            }                                                                   \
        }                                                                       \
    }

__global__ __launch_bounds__(256) void mid_kernel(
    const float* __restrict__ x, const float* __restrict__ emb,
    const float* __restrict__ coef, const float2* __restrict__ V,
    const int* __restrict__ bins, unsigned short* __restrict__ Aimg)
{
    __shared__ unsigned short M1t[64 * 72];
    __shared__ unsigned short Yt[128 * 72];
    __shared__ float cosT[64];
    __shared__ float sinT[64];
    __shared__ float2 Vs[17 * 32];   // whole V slice for this (b,n)
    __shared__ int Bns[17 * 32];
    __shared__ float xs[512];        // x row for this (b,n)

    const int blk = blockIdx.x;
    const int b = blk >> 5, n = blk & 31;
    const int tid = threadIdx.x;
    const int wave = tid >> 6, lane = tid & 63, l15 = lane & 15, q = lane >> 4;
    const float C64 = 0.09817477042468103f;

    if (tid < 64) {
        float ang = (float)tid * C64;
        cosT[tid] = __cosf(ang);
        sinT[tid] = __sinf(ang);
    }
    // preload V, bins, x-row (one coalesced pass; hot loop is LDS-only)
    {
        const float2* Vg = V + (size_t)blk * 544;
        const int* Bg = bins + (size_t)blk * 544;
        for (int i = tid; i < 544; i += 256) { Vs[i] = Vg[i]; Bns[i] = Bg[i]; }
        for (int i = tid; i < 512; i += 256) xs[i] = x[(size_t)b * 16384 + i * 32 + n];
    }

    float win16[4][4];
    #pragma unroll
    for (int tt = 0; tt < 4; ++tt)
        #pragma unroll
        for (int i = 0; i < 4; ++i) {
            int t = tt * 16 + q * 4 + i;
            win16[tt][i] = 0.5f - 0.5f * __cosf((float)t * C64);
        }
    float renv[2][4];
    #pragma unroll
    for (int hf = 0; hf < 2; ++hf)
        #pragma unroll
        for (int i = 0; i < 4; ++i) {
            int k = hf * 16 + q * 4 + i;
            float w0 = 0.5f - 0.5f * __cosf((float)k * C64);
            float w1v = 0.5f - 0.5f * __cosf((float)(k + 32) * C64);
            renv[hf][i] = 1.0f / (w0 * w0 + w1v * w1v);
        }
    int ebase[2];
    float emb2[2];
    size_t cbase[2];
    const int mt = blk >> 7, mp = blk & 127, s = (mp >> 2) & 3;
    #pragma unroll
    for (int e2 = 0; e2 < 2; ++e2) {
        ebase[e2] = (wave * 2 + e2) * 16 + l15;
        emb2[e2] = emb[ebase[e2]];
        int e = ebase[e2];
        int echunk = e >> 5, clog = (e >> 3) & 3, cs = clog ^ s, el = e & 7;
        cbase[e2] = ((size_t)mt * 2048 + echunk) * 4096 + mp * 32 + cs * 8 + el;
    }

    float roll[2][4][4];
    #pragma unroll
    for (int e2 = 0; e2 < 2; ++e2)
        #pragma unroll
        for (int jj = 0; jj < 4; ++jj)
            #pragma unroll
            for (int i = 0; i < 4; ++i) roll[e2][jj][i] = 0.f;

    const int e1 = tid & 127;
    const int mg = (tid >> 7) << 4;
    const int tM = tid & 63;
    const int kg = wave << 4;

    __syncthreads();

    for (int w = 0; w < 17; ++w) {
        // ---- Y (bf16) ----
        {
            const float4* cf = (const float4*)(coef + ((size_t)(w * 128 + e1)) * 8);
            float4 cA = cf[0];
            float4 cB = cf[1];
            unsigned int rep[8], imp[8];
            #pragma unroll
            for (int j2 = 0; j2 < 8; ++j2) {
                unsigned int rpack = 0, ipack = 0;
                #pragma unroll
                for (int sdx = 0; sdx < 2; ++sdx) {
                    int m = mg + j2 * 2 + sdx;
                    float2 vm = Vs[w * 32 + m];
                    float2 vl = (w > 0) ? Vs[(w - 1) * 32 + m] : make_float2(0.f, 0.f);
                    float2 vp = (w < 16) ? Vs[(w + 1) * 32 + m] : make_float2(0.f, 0.f);
                    float re = cB.z;
                    re = fmaf(vm.x, cA.x, re); re = fmaf(-vm.y, cA.y, re);
                    re = fmaf(vl.x, cA.z, re); re = fmaf(-vl.y, cA.w, re);
                    re = fmaf(vp.x, cB.x, re); re = fmaf(-vp.y, cB.y, re);
                    float im = cB.w;
                    im = fmaf(vm.y, cA.x, im); im = fmaf(vm.x, cA.y, im);
                    im = fmaf(vl.y, cA.z, im); im = fmaf(vl.x, cA.w, im);
                    im = fmaf(vp.y, cB.x, im); im = fmaf(vp.x, cB.y, im);
                    re = fmaxf(re, 0.f);
                    im = fmaxf(im, 0.f);
                    rpack |= (unsigned int)f2bf(re) << (16 * sdx);
                    ipack |= (unsigned int)f2bf(im) << (16 * sdx);
                }
                rep[j2] = rpack; imp[j2] = ipack;
            }
            uint4* dr = (uint4*)&Yt[e1 * 72 + mg];
            dr[0] = make_uint4(rep[0], rep[1], rep[2], rep[3]);
            dr[1] = make_uint4(rep[4], rep[5], rep[6], rep[7]);
            uint4* di = (uint4*)&Yt[e1 * 72 + 32 + mg];
            di[0] = make_uint4(imp[0], imp[1], imp[2], imp[3]);
            di[1] = make_uint4(imp[4], imp[5], imp[6], imp[7]);
        }
        // ---- M1 basis ----
        {
            unsigned int mpk[8];
            #pragma unroll
            for (int j2 = 0; j2 < 8; ++j2) {
                unsigned int pk = 0;
                #pragma unroll
                for (int sdx = 0; sdx < 2; ++sdx) {
                    int k = kg + j2 * 2 + sdx;
                    int m = k & 31;
                    int r = Bns[w * 32 + m];
                    float sc = (r == 0 || r == 32) ? 0.015625f : 0.03125f;
                    int idx = (r * tM) & 63;
                    float val = (k < 32) ? (cosT[idx] * sc) : (-sinT[idx] * sc);
                    pk |= (unsigned int)f2bf(val) << (16 * sdx);
                }
                mpk[j2] = pk;
            }
            uint4* dm = (uint4*)&M1t[tM * 72 + kg];
            dm[0] = make_uint4(mpk[0], mpk[1], mpk[2], mpk[3]);
            dm[1] = make_uint4(mpk[4], mpk[5], mpk[6], mpk[7]);
        }
        __syncthreads();

        // ---- MFMA: OUT[t][e] = M1[t][k] @ Ycomb[k][e] ----
        v4f acc[4][2];
        #pragma unroll
        for (int tt = 0; tt < 4; ++tt)
            #pragma unroll
            for (int e2 = 0; e2 < 2; ++e2) acc[tt][e2] = (v4f){0.f, 0.f, 0.f, 0.f};
        #pragma unroll
        for (int ks = 0; ks < 2; ++ks) {
            v8s bfr[2];
            #pragma unroll
            for (int e2 = 0; e2 < 2; ++e2)
                bfr[e2] = *(const v8s*)&Yt[ebase[e2] * 72 + ks * 32 + q * 8];
            #pragma unroll
            for (int tt = 0; tt < 4; ++tt) {
                v8s af = *(const v8s*)&M1t[(tt * 16 + l15) * 72 + ks * 32 + q * 8];
                #pragma unroll
                for (int e2 = 0; e2 < 2; ++e2)
                    acc[tt][e2] = __builtin_amdgcn_mfma_f32_16x16x32_bf16(
                        af, bfr[e2], acc[tt][e2], 0, 0, 0);
            }
        }

        // ---- OLA ----
        if ((w & 1) == 0) {
            MID_ROLL(0, 1, 2, 3);
            if (w > 0) {
                MID_FLUSH(0, 1);
            } else {
                #pragma unroll
                for (int e2 = 0; e2 < 2; ++e2)
                    #pragma unroll
                    for (int i = 0; i < 4; ++i) {
                        roll[e2][0][i] = 0.f; roll[e2][1][i] = 0.f;
                    }
            }
        } else {
            MID_ROLL(2, 3, 0, 1);
            MID_FLUSH(2, 3);
        }
        __syncthreads();
    }
}

// ---------------------------------------------------------------------------
// Kernel D: FC1 split-K GEMM, 256x256 tile, 512 threads (8 waves), BK=32,
// double-buffered global_load_lds with wave-uniform LDS base.
// grid (4, KS). HPT = float or ushort(bf16) partials.
// ---------------------------------------------------------------------------
template<typename HPT>
__global__ __launch_bounds__(512) void gemm_kernel(
    const unsigned short* __restrict__ Aimg, const unsigned short* __restrict__ w1p,
    HPT* __restrict__ hp, int iters)
{
    __shared__ unsigned short As[2][8192];   // [mhalf(2)][mp(128)][32k]
    __shared__ unsigned short Bs[2][8192];

    const int tid = threadIdx.x;
    const int mt2 = blockIdx.x >> 1, nt2 = blockIdx.x & 1;
    const int ks = blockIdx.y;
    const int wave = tid >> 6, lane = tid & 63;
    const int l15 = lane & 15, q = lane >> 4;
    const int kb0 = ks * iters;

    // DMA: waves 0-3 -> A, 4-7 -> B; sub>>1 = image mt/nt half, sub&1 = 4KB half
    const int isB = wave >> 2;
    const int sub = wave & 3;
    const unsigned short* gsrc = (isB
        ? w1p + ((size_t)(nt2 * 2 + (sub >> 1)) * 2048 + kb0) * 4096
        : Aimg + ((size_t)(mt2 * 2 + (sub >> 1)) * 2048 + kb0) * 4096)
        + (sub & 1) * 2048 + lane * 8;
    const int ldsoff = (sub >> 1) * 4096 + (sub & 1) * 2048;   // wave-uniform

    v4f acc[4][8];
    #pragma unroll
    for (int mf = 0; mf < 4; ++mf)
        #pragma unroll
        for (int nf = 0; nf < 8; ++nf) acc[mf][nf] = (v4f){0.f, 0.f, 0.f, 0.f};

    // prefetch iter 0
    {
        unsigned short* dst = (isB ? Bs[0] : As[0]) + ldsoff;
        #pragma unroll
        for (int j = 0; j < 4; ++j) async16(gsrc + j * 512, dst + j * 512);
    }

    const int wm = wave >> 1, wn = wave & 1;            // compute mapping
    const int ca = (q ^ ((l15 >> 2) & 3)) * 8;          // swizzled chunk
    const int rA = (wm >> 1) * 4096 + ((wm & 1) * 64 + l15) * 32 + ca;
    const int rB = wn * 4096 + l15 * 32 + ca;

    for (int it = 0; it < iters; ++it) {
        __syncthreads();   // waits vmcnt(0): DMA(it) landed; prev buf free
        if (it + 1 < iters) {
            const unsigned short* src = gsrc + (size_t)(it + 1) * 4096;
            unsigned short* dst = (isB ? Bs[(it + 1) & 1] : As[(it + 1) & 1]) + ldsoff;
            #pragma unroll
            for (int j = 0; j < 4; ++j) async16(src + j * 512, dst + j * 512);
        }
        const int cur = it & 1;
        v8s af[4], bf[8];
        #pragma unroll
        for (int f = 0; f < 4; ++f) af[f] = *(const v8s*)&As[cur][rA + f * 512];
        #pragma unroll
        for (int nf = 0; nf < 8; ++nf) bf[nf] = *(const v8s*)&Bs[cur][rB + nf * 512];
        #pragma unroll
        for (int mf = 0; mf < 4; ++mf)
            #pragma unroll
            for (int nf = 0; nf < 8; ++nf)
                acc[mf][nf] = __builtin_amdgcn_mfma_f32_16x16x32_bf16(
                    af[mf], bf[nf], acc[mf][nf], 0, 0, 0);
    }

    #pragma unroll
    for (int mf = 0; mf < 4; ++mf)
        #pragma unroll
        for (int nf = 0; nf < 8; ++nf) {
            int row = mt2 * 256 + wm * 64 + mf * 16 + q * 4;
            int col = nt2 * 256 + wn * 128 + nf * 16 + l15;
            HPT* dst = hp + ((size_t)ks * 512 + row) * 512 + col;
            #pragma unroll
            for (int i = 0; i < 4; ++i) {
                float v = acc[mf][nf][i];
                if (sizeof(HPT) == 4) ((float*)dst)[(size_t)i * 512] = v;
                else ((unsigned short*)dst)[(size_t)i * 512] = f2bf(v);
            }
        }
}

// ---------------------------------------------------------------------------
// Kernel E: reduce split-K + b1 + leaky, FC2 + b2, out[b][p][n].
// ---------------------------------------------------------------------------
template<typename HPT>
__global__ __launch_bounds__(128) void fc2_kernel(
    const HPT* __restrict__ hp, const float* __restrict__ b1,
    const float* __restrict__ w2, const float* __restrict__ b2,
    float* __restrict__ out, int KS)
{
    __shared__ float hbuf[512];
    const int row = blockIdx.x;
    const int tid = threadIdx.x;
    #pragma unroll
    for (int ii = 0; ii < 4; ++ii) {
        int hid = tid + ii * 128;
        float s = b1[hid];
        for (int k = 0; k < KS; ++k) {
            HPT v = hp[((size_t)k * 512 + row) * 512 + hid];
            s += (sizeof(HPT) == 4) ? (float)v : bf2f((unsigned short)v);
        }
        hbuf[hid] = (s > 0.f) ? s : 0.01f * s;
    }
    __syncthreads();
    if (tid < 96) {
        float a = b2[tid];
        #pragma unroll 8
        for (int h = 0; h < 512; ++h) a = fmaf(hbuf[h], w2[h * 96 + tid], a);
        int b = row >> 5, n = row & 31;
        out[(size_t)b * 3072 + tid * 32 + n] = a;
    }
}

// ---------------------------------------------------------------------------
extern "C" void kernel_launch(void* const* d_in, const int* in_sizes, int n_in,
                              void* d_out, int out_size, void* d_ws, size_t ws_size,
                              hipStream_t stream) {
    const float* x   = (const float*)d_in[0];
    const float* emb = (const float*)d_in[1];
    const float* Wr  = (const float*)d_in[2];
    const float* Wi  = (const float*)d_in[3];
    const float* Wrl = (const float*)d_in[4];
    const float* Wil = (const float*)d_in[5];
    const float* Wrr = (const float*)d_in[6];
    const float* Wir = (const float*)d_in[7];
    const float* br  = (const float*)d_in[8];
    const float* bi  = (const float*)d_in[9];
    const float* w1  = (const float*)d_in[10];
    const float* b1  = (const float*)d_in[11];
    const float* w2  = (const float*)d_in[12];
    const float* b2  = (const float*)d_in[13];

    char* ws = (char*)d_ws;
    float* coef          = (float*)(ws + OFF_COEF);
    float2* V            = (float2*)(ws + OFF_V);
    int* bins            = (int*)(ws + OFF_BINS);
    unsigned short* Aimg = (unsigned short*)(ws + OFF_AIMG);
    unsigned short* w1p  = (unsigned short*)(ws + OFF_W1P);
    void* hpp            = (void*)(ws + OFF_HP);

    coef_kernel<<<dim3(17, 8), dim3(128), 0, stream>>>(
        emb, Wr, Wi, Wrl, Wil, Wrr, Wir, br, bi, coef);
    cvt_kernel<<<dim3(2048, 4), dim3(256), 0, stream>>>(w1, w1p);
    stft_kernel<<<dim3(512), dim3(256), 0, stream>>>(x, V, bins);
    mid_kernel<<<dim3(512), dim3(256), 0, stream>>>(x, emb, coef, V, bins, Aimg);

    const size_t need_f32 = OFF_HP + 64ull * 512 * 512 * 4;   // 201.6 MB
    const size_t need_b16 = OFF_HP + 64ull * 512 * 512 * 2;   // 169.6 MB
    if (ws_size >= need_f32) {
        int KS = 64, iters = 2048 / KS;
        gemm_kernel<float><<<dim3(4, KS), dim3(512), 0, stream>>>(
            Aimg, w1p, (float*)hpp, iters);
        fc2_kernel<float><<<dim3(512), dim3(128), 0, stream>>>(
            (float*)hpp, b1, w2, b2, (float*)d_out, KS);
    } else if (ws_size >= need_b16) {
        int KS = 64, iters = 2048 / KS;
        gemm_kernel<unsigned short><<<dim3(4, KS), dim3(512), 0, stream>>>(
            Aimg, w1p, (unsigned short*)hpp, iters);
        fc2_kernel<unsigned short><<<dim3(512), dim3(128), 0, stream>>>(
            (unsigned short*)hpp, b1, w2, b2, (float*)d_out, KS);
    } else {
        int KS = 32, iters = 2048 / KS;   // last resort: 128 blocks
        gemm_kernel<unsigned short><<<dim3(4, KS), dim3(512), 0, stream>>>(
            Aimg, w1p, (unsigned short*)hpp, iters);
        fc2_kernel<unsigned short><<<dim3(512), dim3(128), 0, stream>>>(
            (unsigned short*)hpp, b1, w2, b2, (float*)d_out, KS);
    }
}

// Round 5
// 417.787 us; speedup vs baseline: 1.2896x; 1.1319x over previous
//
#include <hip/hip_runtime.h>
#include <hip/hip_bf16.h>

// B=16, SEQ=512, NF=32, E=128, HID=512, PRED=96, N_FFT=64, HOP=32, TOPM=32
// W=17, F=33, LAM=0.01
#define LAM 0.01f

typedef __attribute__((ext_vector_type(8))) short v8s;
typedef __attribute__((ext_vector_type(4))) float v4f;

static __device__ __forceinline__ unsigned short f2bf(float f) {
    union { float f; unsigned int u; } v; v.f = f;
    unsigned int u = v.u;
    u += 0x7fffu + ((u >> 16) & 1u);   // RNE
    return (unsigned short)(u >> 16);
}
static __device__ __forceinline__ float bf2f(unsigned short h) {
    union { unsigned int u; float f; } c; c.u = ((unsigned int)h) << 16;
    return c.f;
}

// async global->LDS DMA, 16 B/lane; lds base wave-uniform, lane i -> base+16i
static __device__ __forceinline__ void async16(const void* g, void* l) {
    __builtin_amdgcn_global_load_lds(
        (const __attribute__((address_space(1))) unsigned int*)g,
        (__attribute__((address_space(3))) unsigned int*)l, 16, 0, 0);
}

// Workspace layout (bytes)
#define OFF_COEF 0ull
#define OFF_V    69632ull
#define OFF_BINS 2297856ull
#define OFF_AIMG 3411968ull                     // 512*65536 bf16 swizzled = 67,108,864
#define OFF_W1P  70520832ull                    // 65536*512 bf16 swizzled = 67,108,864
#define OFF_HP   137629696ull                   // KS*512*512*2 (bf16 partials)
// OFF_H computed at launch (after hp): 512*512*4 f32 = 1 MiB

// ---------------------------------------------------------------------------
// Kernel A: coef[w][e][j]: j=0..5 -> emb . Wj[w,:,e]; j=6 -> br-LAM; j=7 -> bi-LAM
// ---------------------------------------------------------------------------
__global__ __launch_bounds__(128) void coef_kernel(
    const float* __restrict__ emb,
    const float* __restrict__ Wr, const float* __restrict__ Wi,
    const float* __restrict__ Wrl, const float* __restrict__ Wil,
    const float* __restrict__ Wrr, const float* __restrict__ Wir,
    const float* __restrict__ br, const float* __restrict__ bi,
    float* __restrict__ coef)
{
    int w = blockIdx.x, j = blockIdx.y, e = threadIdx.x;
    float out;
    if (j < 6) {
        const float* Wj;
        switch (j) {
            case 0: Wj = Wr; break; case 1: Wj = Wi; break;
            case 2: Wj = Wrl; break; case 3: Wj = Wil; break;
            case 4: Wj = Wrr; break; default: Wj = Wir; break;
        }
        const float* p = Wj + (size_t)w * 16384 + e;
        float acc = 0.f;
        #pragma unroll 8
        for (int ep = 0; ep < 128; ++ep) acc = fmaf(emb[ep], p[ep * 128], acc);
        out = acc;
    } else if (j == 6) {
        out = br[w * 128 + e] - LAM;
    } else {
        out = bi[w * 128 + e] - LAM;
    }
    coef[((size_t)(w * 128 + e)) * 8 + j] = out;
}

// ---------------------------------------------------------------------------
// Kernel B: per (b,n): windowed 64-pt DFT, 17x33 bins, rank |S|, store top-32.
// ---------------------------------------------------------------------------
__global__ __launch_bounds__(256) void stft_kernel(
    const float* __restrict__ x, float2* __restrict__ V, int* __restrict__ bins)
{
    __shared__ float sig[576];
    __shared__ float winT[64];
    __shared__ float2 tw[64];
    __shared__ float2 Sbuf[17 * 33];
    __shared__ float absb[17 * 33];

    const int blk = blockIdx.x;
    const int b = blk >> 5, n = blk & 31;
    const int tid = threadIdx.x;
    const float C64 = 0.09817477042468103f; // 2*pi/64

    if (tid < 64) {
        float ang = (float)tid * C64;
        winT[tid] = 0.5f - 0.5f * cosf(ang);
        tw[tid] = make_float2(cosf(ang), sinf(ang));   // accurate libm: top-k tie safety
    }
    for (int l = tid; l < 576; l += 256) {
        int t = (l < 32) ? (32 - l) : ((l < 544) ? (l - 32) : (1054 - l)); // reflect
        sig[l] = x[(size_t)b * 16384 + t * 32 + n];
    }
    __syncthreads();

    for (int task = tid; task < 561; task += 256) {
        int w = task / 33, f = task - w * 33;
        float sr = 0.f, si = 0.f;
        int base = w * 32;
        for (int t = 0; t < 64; ++t) {
            float sw = sig[base + t] * winT[t];
            float2 cs = tw[(f * t) & 63];
            sr = fmaf(sw, cs.x, sr);
            si = fmaf(sw, -cs.y, si);
        }
        Sbuf[task] = make_float2(sr, si);
        absb[task] = sqrtf(fmaf(sr, sr, si * si));
    }
    __syncthreads();

    for (int task = tid; task < 561; task += 256) {
        int w = task / 33, f = task - w * 33;
        float a = absb[task];
        int base = w * 33, rank = 0;
        for (int j = 0; j < 33; ++j) {
            float aj = absb[base + j];
            rank += (aj > a) || (aj == a && j < f);   // stable
        }
        if (rank < 32) {
            size_t o = ((size_t)blk * 17 + w) * 32 + rank;
            V[o] = Sbuf[task];
            bins[o] = f;
        }
    }
}

// ---------------------------------------------------------------------------
// Kernel W-cvt: w1 f32 -> bf16 swizzled DMA image.
// Image: [nt(4)][kb(2048)][n'(128)][32k]; chunk c_log at pos c_log^((n'>>2)&3).
// ---------------------------------------------------------------------------
__global__ __launch_bounds__(256) void cvt_kernel(
    const float* __restrict__ w1, unsigned short* __restrict__ w1p)
{
    __shared__ float T[32][132];
    const int kb = blockIdx.x, nt = blockIdx.y;
    const int tid = threadIdx.x;

    #pragma unroll
    for (int p = 0; p < 4; ++p) {
        int r = (tid >> 5) + p * 8;
        int c = (tid & 31) * 4;
        float4 v = *(const float4*)&w1[((size_t)(kb * 32 + r)) * 512 + nt * 128 + c];
        T[r][c] = v.x; T[r][c + 1] = v.y; T[r][c + 2] = v.z; T[r][c + 3] = v.w;
    }
    __syncthreads();

    unsigned short* dst = w1p + ((size_t)nt * 2048 + kb) * 4096;
    #pragma unroll
    for (int p = 0; p < 2; ++p) {
        int pos = tid + 256 * p;            // 16-B chunk index
        int np = pos >> 2, cs = pos & 3;
        int clog = cs ^ ((np >> 2) & 3);
        unsigned int pk[4];
        #pragma unroll
        for (int j2 = 0; j2 < 4; ++j2) {
            unsigned short lo = f2bf(T[clog * 8 + j2 * 2][np]);
            unsigned short hi = f2bf(T[clog * 8 + j2 * 2 + 1][np]);
            pk[j2] = (unsigned int)lo | ((unsigned int)hi << 16);
        }
        *(uint4*)&dst[pos * 8] = make_uint4(pk[0], pk[1], pk[2], pk[3]);
    }
}

// ---------------------------------------------------------------------------
// Kernel C: mid — per-(b,n) inputs (V, bins, x-row) preloaded to LDS;
// y bf16; irfft basis; MFMA 64x128; hann; register OLA; /env; + x*emb;
// write A-image bf16 swizzled [mt(4)][kb(2048)][m'(128)][32k]. grid 512, 256 thr.
// ---------------------------------------------------------------------------
#define MID_ROLL(J0, J1, J2, J3)                                                \
    {                                                                           \
        _Pragma("unroll") for (int e2 = 0; e2 < 2; ++e2)                        \
        _Pragma("unroll") for (int i = 0; i < 4; ++i) {                         \
            roll[e2][J0][i] = fmaf(acc[0][e2][i], win16[0][i], roll[e2][J0][i]);\
            roll[e2][J1][i] = fmaf(acc[1][e2][i], win16[1][i], roll[e2][J1][i]);\
            roll[e2][J2][i] = fmaf(acc[2][e2][i], win16[2][i], roll[e2][J2][i]);\
            roll[e2][J3][i] = fmaf(acc[3][e2][i], win16[3][i], roll[e2][J3][i]);\
        }                                                                       \
    }

#define MID_FLUSH(JJA, JJB)                                                     \
    {                                                                           \
        _Pragma("unroll") for (int i = 0; i < 4; ++i) {                         \
            int tp = 32 * (w - 1) + q * 4 + i;                                  \
            float xb = xs[tp];                                                  \
            _Pragma("unroll") for (int e2 = 0; e2 < 2; ++e2) {                  \
                float val = fmaf(roll[e2][JJA][i], renv[0][i], xb * emb2[e2]);  \
                Aimg[cbase[e2] + (size_t)tp * 16384] = f2bf(val);               \
                roll[e2][JJA][i] = 0.f;                                         \
            }                                                                   \
            int tp2 = tp + 16;                                                  \
            float xb2 = xs[tp2];                                                \
            _Pragma("unroll") for (int e2 = 0; e2 < 2; ++e2) {                  \
                float val = fmaf(roll[e2][JJB][i], renv[1][i], xb2 * emb2[e2]); \
                Aimg[cbase[e2] + (size_t)tp2 * 16384] = f2bf(val);              \
                roll[e2][JJB][i] = 0.f;                                         \
            }                                                                   \
        }                                                                       \
    }

__global__ __launch_bounds__(256) void mid_kernel(
    const float* __restrict__ x, const float* __restrict__ emb,
    const float* __restrict__ coef, const float2* __restrict__ V,
    const int* __restrict__ bins, unsigned short* __restrict__ Aimg)
{
    __shared__ unsigned short M1t[64 * 72];
    __shared__ unsigned short Yt[128 * 72];
    __shared__ float cosT[64];
    __shared__ float sinT[64];
    __shared__ float2 Vs[17 * 32];
    __shared__ int Bns[17 * 32];
    __shared__ float xs[512];

    const int blk = blockIdx.x;
    const int b = blk >> 5, n = blk & 31;
    const int tid = threadIdx.x;
    const int wave = tid >> 6, lane = tid & 63, l15 = lane & 15, q = lane >> 4;
    const float C64 = 0.09817477042468103f;

    if (tid < 64) {
        float ang = (float)tid * C64;
        cosT[tid] = __cosf(ang);
        sinT[tid] = __sinf(ang);
    }
    {
        const float2* Vg = V + (size_t)blk * 544;
        const int* Bg = bins + (size_t)blk * 544;
        for (int i = tid; i < 544; i += 256) { Vs[i] = Vg[i]; Bns[i] = Bg[i]; }
        for (int i = tid; i < 512; i += 256) xs[i] = x[(size_t)b * 16384 + i * 32 + n];
    }

    float win16[4][4];
    #pragma unroll
    for (int tt = 0; tt < 4; ++tt)
        #pragma unroll
        for (int i = 0; i < 4; ++i) {
            int t = tt * 16 + q * 4 + i;
            win16[tt][i] = 0.5f - 0.5f * __cosf((float)t * C64);
        }
    float renv[2][4];
    #pragma unroll
    for (int hf = 0; hf < 2; ++hf)
        #pragma unroll
        for (int i = 0; i < 4; ++i) {
            int k = hf * 16 + q * 4 + i;
            float w0 = 0.5f - 0.5f * __cosf((float)k * C64);
            float w1v = 0.5f - 0.5f * __cosf((float)(k + 32) * C64);
            renv[hf][i] = 1.0f / (w0 * w0 + w1v * w1v);
        }
    int ebase[2];
    float emb2[2];
    size_t cbase[2];
    const int mt = blk >> 7, mp = blk & 127, s = (mp >> 2) & 3;
    #pragma unroll
    for (int e2 = 0; e2 < 2; ++e2) {
        ebase[e2] = (wave * 2 + e2) * 16 + l15;
        emb2[e2] = emb[ebase[e2]];
        int e = ebase[e2];
        int echunk = e >> 5, clog = (e >> 3) & 3, cs = clog ^ s, el = e & 7;
        cbase[e2] = ((size_t)mt * 2048 + echunk) * 4096 + mp * 32 + cs * 8 + el;
    }

    float roll[2][4][4];
    #pragma unroll
    for (int e2 = 0; e2 < 2; ++e2)
        #pragma unroll
        for (int jj = 0; jj < 4; ++jj)
            #pragma unroll
            for (int i = 0; i < 4; ++i) roll[e2][jj][i] = 0.f;

    const int e1 = tid & 127;
    const int mg = (tid >> 7) << 4;
    const int tM = tid & 63;
    const int kg = wave << 4;

    __syncthreads();

    for (int w = 0; w < 17; ++w) {
        // ---- Y (bf16) ----
        {
            const float4* cf = (const float4*)(coef + ((size_t)(w * 128 + e1)) * 8);
            float4 cA = cf[0];
            float4 cB = cf[1];
            unsigned int rep[8], imp[8];
            #pragma unroll
            for (int j2 = 0; j2 < 8; ++j2) {
                unsigned int rpack = 0, ipack = 0;
                #pragma unroll
                for (int sdx = 0; sdx < 2; ++sdx) {
                    int m = mg + j2 * 2 + sdx;
                    float2 vm = Vs[w * 32 + m];
                    float2 vl = (w > 0) ? Vs[(w - 1) * 32 + m] : make_float2(0.f, 0.f);
                    float2 vp = (w < 16) ? Vs[(w + 1) * 32 + m] : make_float2(0.f, 0.f);
                    float re = cB.z;
                    re = fmaf(vm.x, cA.x, re); re = fmaf(-vm.y, cA.y, re);
                    re = fmaf(vl.x, cA.z, re); re = fmaf(-vl.y, cA.w, re);
                    re = fmaf(vp.x, cB.x, re); re = fmaf(-vp.y, cB.y, re);
                    float im = cB.w;
                    im = fmaf(vm.y, cA.x, im); im = fmaf(vm.x, cA.y, im);
                    im = fmaf(vl.y, cA.z, im); im = fmaf(vl.x, cA.w, im);
                    im = fmaf(vp.y, cB.x, im); im = fmaf(vp.x, cB.y, im);
                    re = fmaxf(re, 0.f);
                    im = fmaxf(im, 0.f);
                    rpack |= (unsigned int)f2bf(re) << (16 * sdx);
                    ipack |= (unsigned int)f2bf(im) << (16 * sdx);
                }
                rep[j2] = rpack; imp[j2] = ipack;
            }
            uint4* dr = (uint4*)&Yt[e1 * 72 + mg];
            dr[0] = make_uint4(rep[0], rep[1], rep[2], rep[3]);
            dr[1] = make_uint4(rep[4], rep[5], rep[6], rep[7]);
            uint4* di = (uint4*)&Yt[e1 * 72 + 32 + mg];
            di[0] = make_uint4(imp[0], imp[1], imp[2], imp[3]);
            di[1] = make_uint4(imp[4], imp[5], imp[6], imp[7]);
        }
        // ---- M1 basis ----
        {
            unsigned int mpk[8];
            #pragma unroll
            for (int j2 = 0; j2 < 8; ++j2) {
                unsigned int pk = 0;
                #pragma unroll
                for (int sdx = 0; sdx < 2; ++sdx) {
                    int k = kg + j2 * 2 + sdx;
                    int m = k & 31;
                    int r = Bns[w * 32 + m];
                    float sc = (r == 0 || r == 32) ? 0.015625f : 0.03125f;
                    int idx = (r * tM) & 63;
                    float val = (k < 32) ? (cosT[idx] * sc) : (-sinT[idx] * sc);
                    pk |= (unsigned int)f2bf(val) << (16 * sdx);
                }
                mpk[j2] = pk;
            }
            uint4* dm = (uint4*)&M1t[tM * 72 + kg];
            dm[0] = make_uint4(mpk[0], mpk[1], mpk[2], mpk[3]);
            dm[1] = make_uint4(mpk[4], mpk[5], mpk[6], mpk[7]);
        }
        __syncthreads();

        v4f acc[4][2];
        #pragma unroll
        for (int tt = 0; tt < 4; ++tt)
            #pragma unroll
            for (int e2 = 0; e2 < 2; ++e2) acc[tt][e2] = (v4f){0.f, 0.f, 0.f, 0.f};
        #pragma unroll
        for (int ks = 0; ks < 2; ++ks) {
            v8s bfr[2];
            #pragma unroll
            for (int e2 = 0; e2 < 2; ++e2)
                bfr[e2] = *(const v8s*)&Yt[ebase[e2] * 72 + ks * 32 + q * 8];
            #pragma unroll
            for (int tt = 0; tt < 4; ++tt) {
                v8s af = *(const v8s*)&M1t[(tt * 16 + l15) * 72 + ks * 32 + q * 8];
                #pragma unroll
                for (int e2 = 0; e2 < 2; ++e2)
                    acc[tt][e2] = __builtin_amdgcn_mfma_f32_16x16x32_bf16(
                        af, bfr[e2], acc[tt][e2], 0, 0, 0);
            }
        }

        if ((w & 1) == 0) {
            MID_ROLL(0, 1, 2, 3);
            if (w > 0) {
                MID_FLUSH(0, 1);
            } else {
                #pragma unroll
                for (int e2 = 0; e2 < 2; ++e2)
                    #pragma unroll
                    for (int i = 0; i < 4; ++i) {
                        roll[e2][0][i] = 0.f; roll[e2][1][i] = 0.f;
                    }
            }
        } else {
            MID_ROLL(2, 3, 0, 1);
            MID_FLUSH(2, 3);
        }
        __syncthreads();
    }
}

// ---------------------------------------------------------------------------
// Kernel D: FC1 split-K GEMM, 256x256 tile, 512 threads, BK=32, dbuf DMA.
// grid (4, KS). Partials in bf16.
// ---------------------------------------------------------------------------
__global__ __launch_bounds__(512) void gemm_kernel(
    const unsigned short* __restrict__ Aimg, const unsigned short* __restrict__ w1p,
    unsigned short* __restrict__ hp, int iters)
{
    __shared__ unsigned short As[2][8192];
    __shared__ unsigned short Bs[2][8192];

    const int tid = threadIdx.x;
    const int mt2 = blockIdx.x >> 1, nt2 = blockIdx.x & 1;
    const int ks = blockIdx.y;
    const int wave = tid >> 6, lane = tid & 63;
    const int l15 = lane & 15, q = lane >> 4;
    const int kb0 = ks * iters;

    const int isB = wave >> 2;
    const int sub = wave & 3;
    const unsigned short* gsrc = (isB
        ? w1p + ((size_t)(nt2 * 2 + (sub >> 1)) * 2048 + kb0) * 4096
        : Aimg + ((size_t)(mt2 * 2 + (sub >> 1)) * 2048 + kb0) * 4096)
        + (sub & 1) * 2048 + lane * 8;
    const int ldsoff = (sub >> 1) * 4096 + (sub & 1) * 2048;   // wave-uniform

    v4f acc[4][8];
    #pragma unroll
    for (int mf = 0; mf < 4; ++mf)
        #pragma unroll
        for (int nf = 0; nf < 8; ++nf) acc[mf][nf] = (v4f){0.f, 0.f, 0.f, 0.f};

    {
        unsigned short* dst = (isB ? Bs[0] : As[0]) + ldsoff;
        #pragma unroll
        for (int j = 0; j < 4; ++j) async16(gsrc + j * 512, dst + j * 512);
    }

    const int wm = wave >> 1, wn = wave & 1;
    const int ca = (q ^ ((l15 >> 2) & 3)) * 8;
    const int rA = (wm >> 1) * 4096 + ((wm & 1) * 64 + l15) * 32 + ca;
    const int rB = wn * 4096 + l15 * 32 + ca;

    for (int it = 0; it < iters; ++it) {
        __syncthreads();
        if (it + 1 < iters) {
            const unsigned short* src = gsrc + (size_t)(it + 1) * 4096;
            unsigned short* dst = (isB ? Bs[(it + 1) & 1] : As[(it + 1) & 1]) + ldsoff;
            #pragma unroll
            for (int j = 0; j < 4; ++j) async16(src + j * 512, dst + j * 512);
        }
        const int cur = it & 1;
        v8s af[4], bf[8];
        #pragma unroll
        for (int f = 0; f < 4; ++f) af[f] = *(const v8s*)&As[cur][rA + f * 512];
        #pragma unroll
        for (int nf = 0; nf < 8; ++nf) bf[nf] = *(const v8s*)&Bs[cur][rB + nf * 512];
        #pragma unroll
        for (int mf = 0; mf < 4; ++mf)
            #pragma unroll
            for (int nf = 0; nf < 8; ++nf)
                acc[mf][nf] = __builtin_amdgcn_mfma_f32_16x16x32_bf16(
                    af[mf], bf[nf], acc[mf][nf], 0, 0, 0);
    }

    #pragma unroll
    for (int mf = 0; mf < 4; ++mf)
        #pragma unroll
        for (int nf = 0; nf < 8; ++nf) {
            int row = mt2 * 256 + wm * 64 + mf * 16 + q * 4;
            int col = nt2 * 256 + wn * 128 + nf * 16 + l15;
            unsigned short* dst = hp + ((size_t)ks * 512 + row) * 512 + col;
            #pragma unroll
            for (int i = 0; i < 4; ++i) dst[(size_t)i * 512] = f2bf(acc[mf][nf][i]);
        }
}

// ---------------------------------------------------------------------------
// Kernel E1: reduce bf16 split-K partials + b1 + leaky -> h (f32, 1 MiB).
// grid 256, block 128; one uint4 (8 bf16) per thread, k-loop unrolled,
// independent loads (latency-parallel, BW-bound).
// ---------------------------------------------------------------------------
__global__ __launch_bounds__(128) void reduce_kernel(
    const unsigned short* __restrict__ hp, const float* __restrict__ b1,
    float* __restrict__ h, int KS)
{
    const int g = blockIdx.x * 128 + threadIdx.x;   // 32768 uint4 positions
    const uint4* base = (const uint4*)hp + g;       // slice stride = 32768 uint4

    float acc[8];
    #pragma unroll
    for (int j = 0; j < 8; ++j) acc[j] = 0.f;

    #pragma unroll 8
    for (int k = 0; k < KS; ++k) {
        uint4 v = base[(size_t)k * 32768];
        acc[0] += bf2f((unsigned short)(v.x & 0xffff));
        acc[1] += bf2f((unsigned short)(v.x >> 16));
        acc[2] += bf2f((unsigned short)(v.y & 0xffff));
        acc[3] += bf2f((unsigned short)(v.y >> 16));
        acc[4] += bf2f((unsigned short)(v.z & 0xffff));
        acc[5] += bf2f((unsigned short)(v.z >> 16));
        acc[6] += bf2f((unsigned short)(v.w & 0xffff));
        acc[7] += bf2f((unsigned short)(v.w >> 16));
    }

    const int flat = g * 8;
    const int hid = flat & 511;
    float4 o0, o1;
    float* po = (float*)&o0;
    #pragma unroll
    for (int j = 0; j < 8; ++j) {
        float s = acc[j] + b1[hid + j];
        ((float*)&o0)[0]; // no-op to keep po scoped
        float r = (s > 0.f) ? s : 0.01f * s;
        if (j < 4) ((float*)&o0)[j] = r; else ((float*)&o1)[j - 4] = r;
    }
    *(float4*)&h[flat] = o0;
    *(float4*)&h[flat + 4] = o1;
}

// ---------------------------------------------------------------------------
// Kernel E2: FC2 matvec: out[b][p][n] = h[row] . w2[:,p] + b2. grid 512, 128 thr.
// h is 1 MiB, L2-hot after reduce.
// ---------------------------------------------------------------------------
__global__ __launch_bounds__(128) void fcmat_kernel(
    const float* __restrict__ h, const float* __restrict__ w2,
    const float* __restrict__ b2, float* __restrict__ out)
{
    __shared__ float hbuf[512];
    const int row = blockIdx.x;
    const int tid = threadIdx.x;
    #pragma unroll
    for (int ii = 0; ii < 4; ++ii)
        hbuf[tid + ii * 128] = h[(size_t)row * 512 + tid + ii * 128];
    __syncthreads();
    if (tid < 96) {
        float a = b2[tid];
        #pragma unroll 8
        for (int hh = 0; hh < 512; ++hh) a = fmaf(hbuf[hh], w2[hh * 96 + tid], a);
        int b = row >> 5, n = row & 31;
        out[(size_t)b * 3072 + tid * 32 + n] = a;
    }
}

// ---------------------------------------------------------------------------
extern "C" void kernel_launch(void* const* d_in, const int* in_sizes, int n_in,
                              void* d_out, int out_size, void* d_ws, size_t ws_size,
                              hipStream_t stream) {
    const float* x   = (const float*)d_in[0];
    const float* emb = (const float*)d_in[1];
    const float* Wr  = (const float*)d_in[2];
    const float* Wi  = (const float*)d_in[3];
    const float* Wrl = (const float*)d_in[4];
    const float* Wil = (const float*)d_in[5];
    const float* Wrr = (const float*)d_in[6];
    const float* Wir = (const float*)d_in[7];
    const float* br  = (const float*)d_in[8];
    const float* bi  = (const float*)d_in[9];
    const float* w1  = (const float*)d_in[10];
    const float* b1  = (const float*)d_in[11];
    const float* w2  = (const float*)d_in[12];
    const float* b2  = (const float*)d_in[13];

    char* ws = (char*)d_ws;
    float* coef          = (float*)(ws + OFF_COEF);
    float2* V            = (float2*)(ws + OFF_V);
    int* bins            = (int*)(ws + OFF_BINS);
    unsigned short* Aimg = (unsigned short*)(ws + OFF_AIMG);
    unsigned short* w1p  = (unsigned short*)(ws + OFF_W1P);
    unsigned short* hpp  = (unsigned short*)(ws + OFF_HP);

    // bf16 partials: KS=64 needs hp 32 MiB + h 1 MiB after OFF_HP
    int KS = 64;
    size_t hp_bytes = (size_t)KS * 512 * 512 * 2;
    if (OFF_HP + hp_bytes + (1ull << 20) > ws_size) {
        KS = 32; hp_bytes = (size_t)KS * 512 * 512 * 2;
    }
    int iters = 2048 / KS;
    float* hbase = (float*)(ws + OFF_HP + hp_bytes);

    coef_kernel<<<dim3(17, 8), dim3(128), 0, stream>>>(
        emb, Wr, Wi, Wrl, Wil, Wrr, Wir, br, bi, coef);
    cvt_kernel<<<dim3(2048, 4), dim3(256), 0, stream>>>(w1, w1p);
    stft_kernel<<<dim3(512), dim3(256), 0, stream>>>(x, V, bins);
    mid_kernel<<<dim3(512), dim3(256), 0, stream>>>(x, emb, coef, V, bins, Aimg);
    gemm_kernel<<<dim3(4, KS), dim3(512), 0, stream>>>(Aimg, w1p, hpp, iters);
    reduce_kernel<<<dim3(256), dim3(128), 0, stream>>>(hpp, b1, hbase, KS);
    fcmat_kernel<<<dim3(512), dim3(128), 0, stream>>>(hbase, w2, b2, (float*)d_out);
}

// Round 6
// 417.393 us; speedup vs baseline: 1.2908x; 1.0009x over previous
//
#include <hip/hip_runtime.h>
#include <hip/hip_bf16.h>

// B=16, SEQ=512, NF=32, E=128, HID=512, PRED=96, N_FFT=64, HOP=32, TOPM=32
// W=17, F=33, LAM=0.01
#define LAM 0.01f

typedef __attribute__((ext_vector_type(8))) short v8s;
typedef __attribute__((ext_vector_type(4))) float v4f;

static __device__ __forceinline__ unsigned short f2bf(float f) {
    union { float f; unsigned int u; } v; v.f = f;
    unsigned int u = v.u;
    u += 0x7fffu + ((u >> 16) & 1u);   // RNE
    return (unsigned short)(u >> 16);
}
static __device__ __forceinline__ float bf2f(unsigned short h) {
    union { unsigned int u; float f; } c; c.u = ((unsigned int)h) << 16;
    return c.f;
}

// async global->LDS DMA, 16 B/lane; lds base wave-uniform, lane i -> base+16i
static __device__ __forceinline__ void async16(const void* g, void* l) {
    __builtin_amdgcn_global_load_lds(
        (const __attribute__((address_space(1))) unsigned int*)g,
        (__attribute__((address_space(3))) unsigned int*)l, 16, 0, 0);
}

// Workspace layout (bytes)
#define OFF_COEF 0ull
#define OFF_V    69632ull
#define OFF_BINS 2297856ull
#define OFF_AIMG 3411968ull                     // 512*65536 bf16 swizzled = 67,108,864
#define OFF_W1P  70520832ull                    // 65536*512 bf16 swizzled = 67,108,864
#define OFF_HP   137629696ull                   // KS*512*512*2 (bf16 partials)

// ---------------------------------------------------------------------------
// Kernel A: coef[w][e][j]: j=0..5 -> emb . Wj[w,:,e]; j=6 -> br-LAM; j=7 -> bi-LAM
// ---------------------------------------------------------------------------
__global__ __launch_bounds__(128) void coef_kernel(
    const float* __restrict__ emb,
    const float* __restrict__ Wr, const float* __restrict__ Wi,
    const float* __restrict__ Wrl, const float* __restrict__ Wil,
    const float* __restrict__ Wrr, const float* __restrict__ Wir,
    const float* __restrict__ br, const float* __restrict__ bi,
    float* __restrict__ coef)
{
    int w = blockIdx.x, j = blockIdx.y, e = threadIdx.x;
    float out;
    if (j < 6) {
        const float* Wj;
        switch (j) {
            case 0: Wj = Wr; break; case 1: Wj = Wi; break;
            case 2: Wj = Wrl; break; case 3: Wj = Wil; break;
            case 4: Wj = Wrr; break; default: Wj = Wir; break;
        }
        const float* p = Wj + (size_t)w * 16384 + e;
        float acc = 0.f;
        #pragma unroll 8
        for (int ep = 0; ep < 128; ++ep) acc = fmaf(emb[ep], p[ep * 128], acc);
        out = acc;
    } else if (j == 6) {
        out = br[w * 128 + e] - LAM;
    } else {
        out = bi[w * 128 + e] - LAM;
    }
    coef[((size_t)(w * 128 + e)) * 8 + j] = out;
}

// ---------------------------------------------------------------------------
// Kernel B: per (b,n): windowed 64-pt DFT, 17x33 bins, rank |S|, store top-32.
// ---------------------------------------------------------------------------
__global__ __launch_bounds__(256) void stft_kernel(
    const float* __restrict__ x, float2* __restrict__ V, int* __restrict__ bins)
{
    __shared__ float sig[576];
    __shared__ float winT[64];
    __shared__ float2 tw[64];
    __shared__ float2 Sbuf[17 * 33];
    __shared__ float absb[17 * 33];

    const int blk = blockIdx.x;
    const int b = blk >> 5, n = blk & 31;
    const int tid = threadIdx.x;
    const float C64 = 0.09817477042468103f; // 2*pi/64

    if (tid < 64) {
        float ang = (float)tid * C64;
        winT[tid] = 0.5f - 0.5f * cosf(ang);
        tw[tid] = make_float2(cosf(ang), sinf(ang));   // accurate libm: top-k tie safety
    }
    for (int l = tid; l < 576; l += 256) {
        int t = (l < 32) ? (32 - l) : ((l < 544) ? (l - 32) : (1054 - l)); // reflect
        sig[l] = x[(size_t)b * 16384 + t * 32 + n];
    }
    __syncthreads();

    for (int task = tid; task < 561; task += 256) {
        int w = task / 33, f = task - w * 33;
        float sr = 0.f, si = 0.f;
        int base = w * 32;
        for (int t = 0; t < 64; ++t) {
            float sw = sig[base + t] * winT[t];
            float2 cs = tw[(f * t) & 63];
            sr = fmaf(sw, cs.x, sr);
            si = fmaf(sw, -cs.y, si);
        }
        Sbuf[task] = make_float2(sr, si);
        absb[task] = sqrtf(fmaf(sr, sr, si * si));
    }
    __syncthreads();

    for (int task = tid; task < 561; task += 256) {
        int w = task / 33, f = task - w * 33;
        float a = absb[task];
        int base = w * 33, rank = 0;
        for (int j = 0; j < 33; ++j) {
            float aj = absb[base + j];
            rank += (aj > a) || (aj == a && j < f);   // stable
        }
        if (rank < 32) {
            size_t o = ((size_t)blk * 17 + w) * 32 + rank;
            V[o] = Sbuf[task];
            bins[o] = f;
        }
    }
}

// ---------------------------------------------------------------------------
// Kernel W-cvt: w1 f32 -> bf16 swizzled DMA image.
// Image: [nt(4)][kb(2048)][n'(128)][32k]; chunk c_log at pos c_log^((n'>>2)&3).
// ---------------------------------------------------------------------------
__global__ __launch_bounds__(256) void cvt_kernel(
    const float* __restrict__ w1, unsigned short* __restrict__ w1p)
{
    __shared__ float T[32][132];
    const int kb = blockIdx.x, nt = blockIdx.y;
    const int tid = threadIdx.x;

    #pragma unroll
    for (int p = 0; p < 4; ++p) {
        int r = (tid >> 5) + p * 8;
        int c = (tid & 31) * 4;
        float4 v = *(const float4*)&w1[((size_t)(kb * 32 + r)) * 512 + nt * 128 + c];
        T[r][c] = v.x; T[r][c + 1] = v.y; T[r][c + 2] = v.z; T[r][c + 3] = v.w;
    }
    __syncthreads();

    unsigned short* dst = w1p + ((size_t)nt * 2048 + kb) * 4096;
    #pragma unroll
    for (int p = 0; p < 2; ++p) {
        int pos = tid + 256 * p;            // 16-B chunk index
        int np = pos >> 2, cs = pos & 3;
        int clog = cs ^ ((np >> 2) & 3);
        unsigned int pk[4];
        #pragma unroll
        for (int j2 = 0; j2 < 4; ++j2) {
            unsigned short lo = f2bf(T[clog * 8 + j2 * 2][np]);
            unsigned short hi = f2bf(T[clog * 8 + j2 * 2 + 1][np]);
            pk[j2] = (unsigned int)lo | ((unsigned int)hi << 16);
        }
        *(uint4*)&dst[pos * 8] = make_uint4(pk[0], pk[1], pk[2], pk[3]);
    }
}

// ---------------------------------------------------------------------------
// Kernel C: mid — w-split: grid 1024 = (bn 512) x (half 2); half h runs
// w in [8h, 8h+8], flushes rows [256h, 256h+256). First iter rolls then
// zeroes slots 0,1 (pad-discard / halo-discard — symmetric for both halves).
// Per-(b,n) inputs preloaded to LDS. 256 thr.
// ---------------------------------------------------------------------------
#define MID_ROLL(J0, J1, J2, J3)                                                \
    {                                                                           \
        _Pragma("unroll") for (int e2 = 0; e2 < 2; ++e2)                        \
        _Pragma("unroll") for (int i = 0; i < 4; ++i) {                         \
            roll[e2][J0][i] = fmaf(acc[0][e2][i], win16[0][i], roll[e2][J0][i]);\
            roll[e2][J1][i] = fmaf(acc[1][e2][i], win16[1][i], roll[e2][J1][i]);\
            roll[e2][J2][i] = fmaf(acc[2][e2][i], win16[2][i], roll[e2][J2][i]);\
            roll[e2][J3][i] = fmaf(acc[3][e2][i], win16[3][i], roll[e2][J3][i]);\
        }                                                                       \
    }

#define MID_FLUSH(JJA, JJB)                                                     \
    {                                                                           \
        _Pragma("unroll") for (int i = 0; i < 4; ++i) {                         \
            int tp = 32 * (w - 1) + q * 4 + i;                                  \
            float xb = xs[tp];                                                  \
            _Pragma("unroll") for (int e2 = 0; e2 < 2; ++e2) {                  \
                float val = fmaf(roll[e2][JJA][i], renv[0][i], xb * emb2[e2]);  \
                Aimg[cbase[e2] + (size_t)tp * 16384] = f2bf(val);               \
                roll[e2][JJA][i] = 0.f;                                         \
            }                                                                   \
            int tp2 = tp + 16;                                                  \
            float xb2 = xs[tp2];                                                \
            _Pragma("unroll") for (int e2 = 0; e2 < 2; ++e2) {                  \
                float val = fmaf(roll[e2][JJB][i], renv[1][i], xb2 * emb2[e2]); \
                Aimg[cbase[e2] + (size_t)tp2 * 16384] = f2bf(val);              \
                roll[e2][JJB][i] = 0.f;                                         \
            }                                                                   \
        }                                                                       \
    }

__global__ __launch_bounds__(256) void mid_kernel(
    const float* __restrict__ x, const float* __restrict__ emb,
    const float* __restrict__ coef, const float2* __restrict__ V,
    const int* __restrict__ bins, unsigned short* __restrict__ Aimg)
{
    __shared__ unsigned short M1t[64 * 72];
    __shared__ unsigned short Yt[128 * 72];
    __shared__ float cosT[64];
    __shared__ float sinT[64];
    __shared__ float2 Vs[17 * 32];
    __shared__ int Bns[17 * 32];
    __shared__ float xs[512];

    const int blk2 = blockIdx.x;
    const int blk = blk2 & 511;          // (b,n)
    const int wbeg = (blk2 >> 9) * 8;    // 0 or 8
    const int b = blk >> 5, n = blk & 31;
    const int tid = threadIdx.x;
    const int wave = tid >> 6, lane = tid & 63, l15 = lane & 15, q = lane >> 4;
    const float C64 = 0.09817477042468103f;

    if (tid < 64) {
        float ang = (float)tid * C64;
        cosT[tid] = __cosf(ang);
        sinT[tid] = __sinf(ang);
    }
    {
        const float2* Vg = V + (size_t)blk * 544;
        const int* Bg = bins + (size_t)blk * 544;
        for (int i = tid; i < 544; i += 256) { Vs[i] = Vg[i]; Bns[i] = Bg[i]; }
        for (int i = tid; i < 512; i += 256) xs[i] = x[(size_t)b * 16384 + i * 32 + n];
    }

    float win16[4][4];
    #pragma unroll
    for (int tt = 0; tt < 4; ++tt)
        #pragma unroll
        for (int i = 0; i < 4; ++i) {
            int t = tt * 16 + q * 4 + i;
            win16[tt][i] = 0.5f - 0.5f * __cosf((float)t * C64);
        }
    float renv[2][4];
    #pragma unroll
    for (int hf = 0; hf < 2; ++hf)
        #pragma unroll
        for (int i = 0; i < 4; ++i) {
            int k = hf * 16 + q * 4 + i;
            float w0 = 0.5f - 0.5f * __cosf((float)k * C64);
            float w1v = 0.5f - 0.5f * __cosf((float)(k + 32) * C64);
            renv[hf][i] = 1.0f / (w0 * w0 + w1v * w1v);
        }
    int ebase[2];
    float emb2[2];
    size_t cbase[2];
    const int mt = blk >> 7, mp = blk & 127, s = (mp >> 2) & 3;
    #pragma unroll
    for (int e2 = 0; e2 < 2; ++e2) {
        ebase[e2] = (wave * 2 + e2) * 16 + l15;
        emb2[e2] = emb[ebase[e2]];
        int e = ebase[e2];
        int echunk = e >> 5, clog = (e >> 3) & 3, cs = clog ^ s, el = e & 7;
        cbase[e2] = ((size_t)mt * 2048 + echunk) * 4096 + mp * 32 + cs * 8 + el;
    }

    float roll[2][4][4];
    #pragma unroll
    for (int e2 = 0; e2 < 2; ++e2)
        #pragma unroll
        for (int jj = 0; jj < 4; ++jj)
            #pragma unroll
            for (int i = 0; i < 4; ++i) roll[e2][jj][i] = 0.f;

    const int e1 = tid & 127;
    const int mg = (tid >> 7) << 4;
    const int tM = tid & 63;
    const int kg = wave << 4;

    __syncthreads();

    for (int w = wbeg; w < wbeg + 9; ++w) {
        // ---- Y (bf16) ----
        {
            const float4* cf = (const float4*)(coef + ((size_t)(w * 128 + e1)) * 8);
            float4 cA = cf[0];
            float4 cB = cf[1];
            unsigned int rep[8], imp[8];
            #pragma unroll
            for (int j2 = 0; j2 < 8; ++j2) {
                unsigned int rpack = 0, ipack = 0;
                #pragma unroll
                for (int sdx = 0; sdx < 2; ++sdx) {
                    int m = mg + j2 * 2 + sdx;
                    float2 vm = Vs[w * 32 + m];
                    float2 vl = (w > 0) ? Vs[(w - 1) * 32 + m] : make_float2(0.f, 0.f);
                    float2 vp = (w < 16) ? Vs[(w + 1) * 32 + m] : make_float2(0.f, 0.f);
                    float re = cB.z;
                    re = fmaf(vm.x, cA.x, re); re = fmaf(-vm.y, cA.y, re);
                    re = fmaf(vl.x, cA.z, re); re = fmaf(-vl.y, cA.w, re);
                    re = fmaf(vp.x, cB.x, re); re = fmaf(-vp.y, cB.y, re);
                    float im = cB.w;
                    im = fmaf(vm.y, cA.x, im); im = fmaf(vm.x, cA.y, im);
                    im = fmaf(vl.y, cA.z, im); im = fmaf(vl.x, cA.w, im);
                    im = fmaf(vp.y, cB.x, im); im = fmaf(vp.x, cB.y, im);
                    re = fmaxf(re, 0.f);
                    im = fmaxf(im, 0.f);
                    rpack |= (unsigned int)f2bf(re) << (16 * sdx);
                    ipack |= (unsigned int)f2bf(im) << (16 * sdx);
                }
                rep[j2] = rpack; imp[j2] = ipack;
            }
            uint4* dr = (uint4*)&Yt[e1 * 72 + mg];
            dr[0] = make_uint4(rep[0], rep[1], rep[2], rep[3]);
            dr[1] = make_uint4(rep[4], rep[5], rep[6], rep[7]);
            uint4* di = (uint4*)&Yt[e1 * 72 + 32 + mg];
            di[0] = make_uint4(imp[0], imp[1], imp[2], imp[3]);
            di[1] = make_uint4(imp[4], imp[5], imp[6], imp[7]);
        }
        // ---- M1 basis ----
        {
            unsigned int mpk[8];
            #pragma unroll
            for (int j2 = 0; j2 < 8; ++j2) {
                unsigned int pk = 0;
                #pragma unroll
                for (int sdx = 0; sdx < 2; ++sdx) {
                    int k = kg + j2 * 2 + sdx;
                    int m = k & 31;
                    int r = Bns[w * 32 + m];
                    float sc = (r == 0 || r == 32) ? 0.015625f : 0.03125f;
                    int idx = (r * tM) & 63;
                    float val = (k < 32) ? (cosT[idx] * sc) : (-sinT[idx] * sc);
                    pk |= (unsigned int)f2bf(val) << (16 * sdx);
                }
                mpk[j2] = pk;
            }
            uint4* dm = (uint4*)&M1t[tM * 72 + kg];
            dm[0] = make_uint4(mpk[0], mpk[1], mpk[2], mpk[3]);
            dm[1] = make_uint4(mpk[4], mpk[5], mpk[6], mpk[7]);
        }
        __syncthreads();

        v4f acc[4][2];
        #pragma unroll
        for (int tt = 0; tt < 4; ++tt)
            #pragma unroll
            for (int e2 = 0; e2 < 2; ++e2) acc[tt][e2] = (v4f){0.f, 0.f, 0.f, 0.f};
        #pragma unroll
        for (int ks = 0; ks < 2; ++ks) {
            v8s bfr[2];
            #pragma unroll
            for (int e2 = 0; e2 < 2; ++e2)
                bfr[e2] = *(const v8s*)&Yt[ebase[e2] * 72 + ks * 32 + q * 8];
            #pragma unroll
            for (int tt = 0; tt < 4; ++tt) {
                v8s af = *(const v8s*)&M1t[(tt * 16 + l15) * 72 + ks * 32 + q * 8];
                #pragma unroll
                for (int e2 = 0; e2 < 2; ++e2)
                    acc[tt][e2] = __builtin_amdgcn_mfma_f32_16x16x32_bf16(
                        af, bfr[e2], acc[tt][e2], 0, 0, 0);
            }
        }

        if ((w & 1) == 0) {
            MID_ROLL(0, 1, 2, 3);
            if (w > wbeg) {
                MID_FLUSH(0, 1);
            } else {
                // first window of this half: slots 0,1 hold rows owned by the
                // other half (or pad) — discard (verified pad-discard logic)
                #pragma unroll
                for (int e2 = 0; e2 < 2; ++e2)
                    #pragma unroll
                    for (int i = 0; i < 4; ++i) {
                        roll[e2][0][i] = 0.f; roll[e2][1][i] = 0.f;
                    }
            }
        } else {
            MID_ROLL(2, 3, 0, 1);
            MID_FLUSH(2, 3);
        }
        __syncthreads();
    }
}

// ---------------------------------------------------------------------------
// Kernel D: FC1 split-K GEMM, 256x256 tile, 512 threads, BK=32, dbuf DMA.
// Flat grid 4*KS with XCD-pairing swizzle: the two nt2-partners of one
// (mt2,ks) A-slice get block ids ≡ (mod 8) -> same XCD under round-robin.
// Partials bf16.
// ---------------------------------------------------------------------------
__global__ __launch_bounds__(512) void gemm_kernel(
    const unsigned short* __restrict__ Aimg, const unsigned short* __restrict__ w1p,
    unsigned short* __restrict__ hp, int iters, int KS)
{
    __shared__ unsigned short As[2][8192];
    __shared__ unsigned short Bs[2][8192];

    const int gid = blockIdx.x;
    const int xcd = gid & 7;
    const int u = gid >> 3;
    const int KS4 = KS >> 2;
    const int nt2 = (u >= KS4) ? 1 : 0;
    const int vv = u - nt2 * KS4;
    const int pid = vv * 8 + xcd;
    const int ks = pid >> 1;
    const int mt2 = pid & 1;

    const int tid = threadIdx.x;
    const int wave = tid >> 6, lane = tid & 63;
    const int l15 = lane & 15, q = lane >> 4;
    const int kb0 = ks * iters;

    const int isB = wave >> 2;
    const int sub = wave & 3;
    const unsigned short* gsrc = (isB
        ? w1p + ((size_t)(nt2 * 2 + (sub >> 1)) * 2048 + kb0) * 4096
        : Aimg + ((size_t)(mt2 * 2 + (sub >> 1)) * 2048 + kb0) * 4096)
        + (sub & 1) * 2048 + lane * 8;
    const int ldsoff = (sub >> 1) * 4096 + (sub & 1) * 2048;   // wave-uniform

    v4f acc[4][8];
    #pragma unroll
    for (int mf = 0; mf < 4; ++mf)
        #pragma unroll
        for (int nf = 0; nf < 8; ++nf) acc[mf][nf] = (v4f){0.f, 0.f, 0.f, 0.f};

    {
        unsigned short* dst = (isB ? Bs[0] : As[0]) + ldsoff;
        #pragma unroll
        for (int j = 0; j < 4; ++j) async16(gsrc + j * 512, dst + j * 512);
    }

    const int wm = wave >> 1, wn = wave & 1;
    const int ca = (q ^ ((l15 >> 2) & 3)) * 8;
    const int rA = (wm >> 1) * 4096 + ((wm & 1) * 64 + l15) * 32 + ca;
    const int rB = wn * 4096 + l15 * 32 + ca;

    for (int it = 0; it < iters; ++it) {
        __syncthreads();
        if (it + 1 < iters) {
            const unsigned short* src = gsrc + (size_t)(it + 1) * 4096;
            unsigned short* dst = (isB ? Bs[(it + 1) & 1] : As[(it + 1) & 1]) + ldsoff;
            #pragma unroll
            for (int j = 0; j < 4; ++j) async16(src + j * 512, dst + j * 512);
        }
        const int cur = it & 1;
        v8s af[4], bf[8];
        #pragma unroll
        for (int f = 0; f < 4; ++f) af[f] = *(const v8s*)&As[cur][rA + f * 512];
        #pragma unroll
        for (int nf = 0; nf < 8; ++nf) bf[nf] = *(const v8s*)&Bs[cur][rB + nf * 512];
        #pragma unroll
        for (int mf = 0; mf < 4; ++mf)
            #pragma unroll
            for (int nf = 0; nf < 8; ++nf)
                acc[mf][nf] = __builtin_amdgcn_mfma_f32_16x16x32_bf16(
                    af[mf], bf[nf], acc[mf][nf], 0, 0, 0);
    }

    #pragma unroll
    for (int mf = 0; mf < 4; ++mf)
        #pragma unroll
        for (int nf = 0; nf < 8; ++nf) {
            int row = mt2 * 256 + wm * 64 + mf * 16 + q * 4;
            int col = nt2 * 256 + wn * 128 + nf * 16 + l15;
            unsigned short* dst = hp + ((size_t)ks * 512 + row) * 512 + col;
            #pragma unroll
            for (int i = 0; i < 4; ++i) dst[(size_t)i * 512] = f2bf(acc[mf][nf][i]);
        }
}

// ---------------------------------------------------------------------------
// Kernel E (fused): per row — reduce bf16 split-K partials + b1 + leaky into
// LDS, then FC2 matvec + b2 -> out[b][p][n]. grid 512, 256 thr.
// ---------------------------------------------------------------------------
__global__ __launch_bounds__(256) void fc2_kernel(
    const unsigned short* __restrict__ hp, const float* __restrict__ b1,
    const float* __restrict__ w2, const float* __restrict__ b2,
    float* __restrict__ out, int KS)
{
    __shared__ float hbuf[512];
    const int row = blockIdx.x;
    const int tid = threadIdx.x;

    // phase 1: reduce over KS slices; thread t owns hids {2t, 2t+1}
    const unsigned int* base = (const unsigned int*)(hp + (size_t)row * 512) + tid;
    float a0 = 0.f, a1 = 0.f;
    #pragma unroll 8
    for (int k = 0; k < KS; ++k) {
        unsigned int v = base[(size_t)k * 131072];   // 512*512 ushort / 2
        a0 += bf2f((unsigned short)(v & 0xffff));
        a1 += bf2f((unsigned short)(v >> 16));
    }
    float s0 = a0 + b1[tid * 2];
    float s1 = a1 + b1[tid * 2 + 1];
    hbuf[tid * 2]     = (s0 > 0.f) ? s0 : 0.01f * s0;
    hbuf[tid * 2 + 1] = (s1 > 0.f) ? s1 : 0.01f * s1;
    __syncthreads();

    // phase 2: matvec
    if (tid < 96) {
        float a = b2[tid];
        #pragma unroll 8
        for (int h = 0; h < 512; ++h) a = fmaf(hbuf[h], w2[h * 96 + tid], a);
        int b = row >> 5, n = row & 31;
        out[(size_t)b * 3072 + tid * 32 + n] = a;
    }
}

// ---------------------------------------------------------------------------
extern "C" void kernel_launch(void* const* d_in, const int* in_sizes, int n_in,
                              void* d_out, int out_size, void* d_ws, size_t ws_size,
                              hipStream_t stream) {
    const float* x   = (const float*)d_in[0];
    const float* emb = (const float*)d_in[1];
    const float* Wr  = (const float*)d_in[2];
    const float* Wi  = (const float*)d_in[3];
    const float* Wrl = (const float*)d_in[4];
    const float* Wil = (const float*)d_in[5];
    const float* Wrr = (const float*)d_in[6];
    const float* Wir = (const float*)d_in[7];
    const float* br  = (const float*)d_in[8];
    const float* bi  = (const float*)d_in[9];
    const float* w1  = (const float*)d_in[10];
    const float* b1  = (const float*)d_in[11];
    const float* w2  = (const float*)d_in[12];
    const float* b2  = (const float*)d_in[13];

    char* ws = (char*)d_ws;
    float* coef          = (float*)(ws + OFF_COEF);
    float2* V            = (float2*)(ws + OFF_V);
    int* bins            = (int*)(ws + OFF_BINS);
    unsigned short* Aimg = (unsigned short*)(ws + OFF_AIMG);
    unsigned short* w1p  = (unsigned short*)(ws + OFF_W1P);
    unsigned short* hpp  = (unsigned short*)(ws + OFF_HP);

    int KS = 64;
    size_t hp_bytes = (size_t)KS * 512 * 512 * 2;
    if (OFF_HP + hp_bytes > ws_size) {
        KS = 32; hp_bytes = (size_t)KS * 512 * 512 * 2;
    }
    int iters = 2048 / KS;

    coef_kernel<<<dim3(17, 8), dim3(128), 0, stream>>>(
        emb, Wr, Wi, Wrl, Wil, Wrr, Wir, br, bi, coef);
    cvt_kernel<<<dim3(2048, 4), dim3(256), 0, stream>>>(w1, w1p);
    stft_kernel<<<dim3(512), dim3(256), 0, stream>>>(x, V, bins);
    mid_kernel<<<dim3(1024), dim3(256), 0, stream>>>(x, emb, coef, V, bins, Aimg);
    gemm_kernel<<<dim3(4 * KS), dim3(512), 0, stream>>>(Aimg, w1p, hpp, iters, KS);
    fc2_kernel<<<dim3(512), dim3(256), 0, stream>>>(hpp, b1, w2, b2, (float*)d_out, KS);
}